// Round 4
// baseline (1232.944 us; speedup 1.0000x reference)
//
#include <hip/hip_runtime.h>
#include <hip/hip_bf16.h>
#include <math.h>

// B=8, H=64, W=64, C=512 -> rows M = 32768; T=77, HH=8, DH=64, TOP_M=3
#define MROWS 32768
#define CDIM  512
#define TTOK  77
#define BTOK  616
#define NTOK  16777216

typedef __attribute__((ext_vector_type(8))) short short8;
typedef __attribute__((ext_vector_type(4))) float float4v;

__device__ __forceinline__ float ldin(const void* p, size_t i, int isf32) {
  return isf32 ? ((const float*)p)[i]
               : __bfloat162float(((const __hip_bfloat16*)p)[i]);
}

// async global->LDS, 16B per lane; LDS dest = uniform base + lane*16
__device__ __forceinline__ void gload16(const void* g, void* l) {
  __builtin_amdgcn_global_load_lds((const __attribute__((address_space(1))) unsigned int*)g,
                                   (__attribute__((address_space(3))) unsigned int*)l,
                                   16, 0, 0);
}

__device__ __forceinline__ float wave_sum(float v) {
#pragma unroll
  for (int off = 32; off > 0; off >>= 1) v += __shfl_xor(v, off, 64);
  return v;
}
__device__ __forceinline__ float wave_max(float v) {
#pragma unroll
  for (int off = 32; off > 0; off >>= 1) v = fmaxf(v, __shfl_xor(v, off, 64));
  return v;
}
__device__ __forceinline__ float block_sum256(float v) {
  __shared__ float red[4];
  int lane = threadIdx.x & 63, wid = threadIdx.x >> 6;
  float s = wave_sum(v);
  if (lane == 0) red[wid] = s;
  __syncthreads();
  s = red[0] + red[1] + red[2] + red[3];
  __syncthreads();
  return s;
}

// dtype detect (proven): 1 => fp32 inputs, 0 => bf16 inputs
__global__ __launch_bounds__(256) void detect_kernel(const unsigned int* __restrict__ t,
                                                     int* __restrict__ flag) {
  int insane = 0;
  for (int i = threadIdx.x; i < 4096; i += 256) {
    unsigned int lo = t[i] & 0xFFFFu;
    int e = (int)((lo >> 7) & 0xFFu);
    int sane = (lo == 0u) || (e >= 87 && e <= 147);
    insane += 1 - sane;
  }
  float tot = block_sum256((float)insane);
  if (threadIdx.x == 0) flag[0] = (tot > 1024.0f) ? 1 : 0;
}

// fused small-parameter convert: one block per segment
struct PC { const void* src; float* dst; int n; };
struct PCTab { PC e[14]; };
__global__ __launch_bounds__(256) void cvt_params_kernel(PCTab t, const int* __restrict__ flag) {
  int f = *flag;
  PC p = t.e[blockIdx.x];
  for (int i = threadIdx.x; i < p.n; i += 256) p.dst[i] = ldin(p.src, i, f);
}

// weight transpose+convert: in (KxN, raw dtype) -> out bf16 (NxK)
__global__ __launch_bounds__(256) void tcvt_kernel(const void* __restrict__ in,
                                                   __hip_bfloat16* __restrict__ out,
                                                   int K, int N, const int* __restrict__ flag) {
  __shared__ float tile[32][33];
  int tx = threadIdx.x & 31, ty = threadIdx.x >> 5;   // 32 x 8
  int k0 = blockIdx.y * 32, n0 = blockIdx.x * 32;
  int f = *flag;
#pragma unroll
  for (int r = 0; r < 4; ++r) {
    int k = k0 + ty + r * 8;
    tile[ty + r * 8][tx] = ldin(in, (size_t)k * N + n0 + tx, f);
  }
  __syncthreads();
#pragma unroll
  for (int r = 0; r < 4; ++r) {
    int n = n0 + ty + r * 8;
    out[(size_t)n * K + k0 + tx] = __float2bfloat16(tile[tx][ty + r * 8]);
  }
}

// pad mask straight from raw text
__global__ __launch_bounds__(256) void pad_kernel(const void* __restrict__ text,
                                                  float* __restrict__ pad,
                                                  const int* __restrict__ flag) {
  int row = blockIdx.x;
  size_t base = (size_t)row * CDIM;
  int tid = threadIdx.x;
  int f = *flag;
  float s = fabsf(ldin(text, base + tid, f)) + fabsf(ldin(text, base + 256 + tid, f));
  float tot = block_sum256(s);
  if (tid == 0) pad[row] = (tot <= 1e-6f) ? 1.0f : 0.0f;
}

// LayerNorm over C=512 (raw flag-dtype input) -> bf16 out
__global__ __launch_bounds__(256) void ln_kernel(const void* __restrict__ in,
                                                 const float* __restrict__ w,
                                                 const float* __restrict__ b,
                                                 __hip_bfloat16* __restrict__ out,
                                                 const int* __restrict__ flag) {
  int row = blockIdx.x;
  size_t base = (size_t)row * CDIM;
  int tid = threadIdx.x;
  int f = *flag;
  float v0 = ldin(in, base + tid, f);
  float v1 = ldin(in, base + 256 + tid, f);
  float tot = block_sum256(v0 + v1);
  float mu = tot * (1.0f / 512.0f);
  float d0 = v0 - mu, d1 = v1 - mu;
  float rs = rsqrtf(block_sum256(d0 * d0 + d1 * d1) * (1.0f / 512.0f) + 1e-5f);
  out[base + tid]       = __float2bfloat16(d0 * rs * w[tid]       + b[tid]);
  out[base + 256 + tid] = __float2bfloat16(d1 * rs * w[256 + tid] + b[256 + tid]);
}

__global__ __launch_bounds__(256) void rownorm_kernel(float* __restrict__ x) {
  int row = blockIdx.x;
  size_t base = (size_t)row * CDIM;
  int tid = threadIdx.x;
  float v0 = x[base + tid], v1 = x[base + 256 + tid];
  float sq = block_sum256(v0 * v0 + v1 * v1);
  float inv = 1.0f / fmaxf(sqrtf(sq), 1e-6f);
  x[base + tid] = v0 * inv;
  x[base + 256 + tid] = v1 * inv;
}

// fused gate + combine + LN2:
//   g   = alpha * sigmoid(x.Wg + bg) * (mean_h conf >= 0.35)
//   y   = x + g*proj   (fp32 back into proj, needed as MLP residual)
//   y2  = LN(y) -> bf16
__global__ __launch_bounds__(256) void combine_ln_kernel(const __hip_bfloat16* __restrict__ x,
                                                         float* __restrict__ proj,
                                                         const float* __restrict__ confh,
                                                         const float* __restrict__ Wg,
                                                         const float* __restrict__ bg,
                                                         const float* __restrict__ alpha_p,
                                                         const float* __restrict__ w,
                                                         const float* __restrict__ b,
                                                         __hip_bfloat16* __restrict__ y2) {
  int row = blockIdx.x;
  size_t base = (size_t)row * CDIM;
  int tid = threadIdx.x;
  float xv0 = __bfloat162float(x[base + tid]);
  float xv1 = __bfloat162float(x[base + 256 + tid]);
  float dot = block_sum256(xv0 * Wg[tid] + xv1 * Wg[256 + tid]);
  float csp = (tid < 8) ? confh[(size_t)tid * MROWS + row] : 0.0f;
  float cs = block_sum256(csp);
  float gate = 1.0f / (1.0f + expf(-(dot + bg[0])));
  float byp = (cs * 0.125f >= 0.35f) ? 1.0f : 0.0f;
  float gv = alpha_p[0] * gate * byp;

  float v0 = xv0 + gv * proj[base + tid];
  float v1 = xv1 + gv * proj[base + 256 + tid];
  proj[base + tid] = v0;
  proj[base + 256 + tid] = v1;
  float tot = block_sum256(v0 + v1);
  float mu = tot * (1.0f / 512.0f);
  float d0 = v0 - mu, d1 = v1 - mu;
  float rs = rsqrtf(block_sum256(d0 * d0 + d1 * d1) * (1.0f / 512.0f) + 1e-5f);
  y2[base + tid]       = __float2bfloat16(d0 * rs * w[tid]       + b[tid]);
  y2[base + 256 + tid] = __float2bfloat16(d1 * rs * w[256 + tid] + b[256 + tid]);
}

// ---------------- attention ----------------
// Round-3 post-mortem: 251us ~= 384 ds_read_b128/wave * 12cyc (LDS-pipe-bound).
// K rows per lane are invariant across the 8 q-rows -> register-block K:
// dg in chunks of 4 float4s, hold ka[4]/kb[4] in regs, accumulate s0a[8]/s1a[8].
// K reads 256->32 per wave; q reads stay at 128 (floor). Total b128 384->160.
// FMA order per dg unchanged -> logits bit-identical to round 3.
// LDS 39424B -> 4 blocks/CU. No forced waves-per-EU cap (round-1 spill lesson).
__global__ __launch_bounds__(256) void attn_kernel(const float* __restrict__ qn,
                                                   const float* __restrict__ kn,
                                                   const float* __restrict__ vf,
                                                   const float* __restrict__ pad,
                                                   const float* __restrict__ ls_p,
                                                   __hip_bfloat16* __restrict__ aligned,
                                                   float* __restrict__ confh) {
  __shared__ float kt[TTOK * 68];
  __shared__ __hip_bfloat16 vt[TTOK * 64];
  __shared__ float qt[32 * 64];
  int tid = threadIdx.x;
  int lane = tid & 63, wid = tid >> 6;
  int blk = blockIdx.x;
  int nchunk = blk & 127;
  int bh = blk >> 7;
  int h = bh & 7, b = bh >> 3;

  for (int idx = tid; idx < TTOK * 64; idx += 256) {
    int t = idx >> 6, d = idx & 63;
    size_t src = ((size_t)(b * TTOK + t)) * CDIM + h * 64 + d;
    kt[t * 68 + d] = kn[src];
    vt[t * 64 + d] = __float2bfloat16(vf[src]);
  }
  for (int idx = tid; idx < 32 * 64; idx += 256) {
    int nl = idx >> 6, d = idx & 63;
    qt[idx] = qn[((size_t)(b * 4096 + nchunk * 32 + nl)) * CDIM + h * 64 + d];
  }
  __syncthreads();

  float ls = fminf(fmaxf(ls_p[0], -2.0f), 2.0f);
  float scale = expf(ls) * 0.125f;
  const float NEGINF = -__builtin_inff();
  float pv0 = pad[b * TTOK + lane];
  int t1ok = (lane + 64 < TTOK);
  float pv1 = t1ok ? pad[b * TTOK + lane + 64] : 1.0f;
  int t1 = t1ok ? lane + 64 : 0;

  // ---- QK phase: K register-blocked, all 8 rows accumulated together ----
  float s0a[8], s1a[8];
#pragma unroll
  for (int i = 0; i < 8; ++i) { s0a[i] = 0.0f; s1a[i] = 0.0f; }
  {
    const float4* k0p = (const float4*)&kt[lane * 68];
    const float4* k1p = (const float4*)&kt[t1 * 68];
    const float4* qb4 = (const float4*)&qt[wid * 8 * 64];
#pragma unroll
    for (int dg0 = 0; dg0 < 16; dg0 += 4) {
      float4 ka0 = k0p[dg0], ka1 = k0p[dg0 + 1], ka2 = k0p[dg0 + 2], ka3 = k0p[dg0 + 3];
      float4 kb0 = k1p[dg0], kb1 = k1p[dg0 + 1], kb2 = k1p[dg0 + 2], kb3 = k1p[dg0 + 3];
#pragma unroll
      for (int i = 0; i < 8; ++i) {
        const float4* qv4 = qb4 + i * 16 + dg0;
        float4 q0 = qv4[0], q1 = qv4[1], q2 = qv4[2], q3 = qv4[3];
        s0a[i] += q0.x * ka0.x + q0.y * ka0.y + q0.z * ka0.z + q0.w * ka0.w;
        s1a[i] += q0.x * kb0.x + q0.y * kb0.y + q0.z * kb0.z + q0.w * kb0.w;
        s0a[i] += q1.x * ka1.x + q1.y * ka1.y + q1.z * ka1.z + q1.w * ka1.w;
        s1a[i] += q1.x * kb1.x + q1.y * kb1.y + q1.z * kb1.z + q1.w * kb1.w;
        s0a[i] += q2.x * ka2.x + q2.y * ka2.y + q2.z * ka2.z + q2.w * ka2.w;
        s1a[i] += q2.x * kb2.x + q2.y * kb2.y + q2.z * kb2.z + q2.w * kb2.w;
        s0a[i] += q3.x * ka3.x + q3.y * ka3.y + q3.z * ka3.z + q3.w * ka3.w;
        s1a[i] += q3.x * kb3.x + q3.y * kb3.y + q3.z * kb3.z + q3.w * kb3.w;
      }
    }
  }

  // ---- per-row softmax / top-3 / entropy / PV epilogue (unchanged logic) ----
  for (int i = 0; i < 8; ++i) {
    int nl = wid * 8 + i;
    int n = nchunk * 32 + nl;
    size_t qbase = ((size_t)(b * 4096 + n)) * CDIM + h * 64;
    float v0 = (pv0 > 0.0f) ? NEGINF : s0a[i] * scale;
    float v1 = (!t1ok || pv1 > 0.0f) ? NEGINF : s1a[i] * scale;

    float m1 = wave_max(fmaxf(v0, v1));
    float acc = 0.0f, conf_h = 0.0f;
    if (m1 != NEGINF) {
      // top-3 threshold (identical logic/order to proven version)
      int c1 = __popcll(__ballot(v0 >= m1)) + __popcll(__ballot(v1 >= m1));
      float thr;
      if (c1 >= 3) thr = m1;
      else {
        float m2 = wave_max(fmaxf(v0 < m1 ? v0 : NEGINF, v1 < m1 ? v1 : NEGINF));
        int c2 = __popcll(__ballot(v0 >= m2)) + __popcll(__ballot(v1 >= m2));
        if (c2 >= 3) thr = m2;
        else thr = wave_max(fmaxf(v0 < m2 ? v0 : NEGINF, v1 < m2 ? v1 : NEGINF));
      }
      bool kp0 = (v0 >= thr) && (v0 != NEGINF);
      bool kp1 = (v1 >= thr) && (v1 != NEGINF);
      float d0 = v0 - m1, d1 = v1 - m1;
      float e0 = kp0 ? expf(d0) : 0.0f;
      float e1 = kp1 ? expf(d1) : 0.0f;
      // fused pair reduction: S1 = sum e, S2 = sum e*(v-m1)
      float S1 = e0 + e1;
      float S2 = e0 * d0 + e1 * d1;
#pragma unroll
      for (int off = 32; off > 0; off >>= 1) {
        S1 += __shfl_xor(S1, off, 64);
        S2 += __shfl_xor(S2, off, 64);
      }
      unsigned long long km0 = __ballot(kp0);
      unsigned long long km1 = __ballot(kp1);
      int cnt = __popcll(km0) + __popcll(km1);
      float invS = 1.0f / S1;
      float maxp = invS;                       // max prob = exp(0)/S1
      // -sum p ln p = ln S1 - S2/S1 ; plus reference's 1e-8 clamp terms for zeros
      float es = (logf(S1) - S2 * invS) + (float)(TTOK - cnt) * 1.8420680743952367e-7f;
      float teff = fmaxf((float)cnt, 2.0f);
      float ent = fmaxf(es / logf(teff), 0.0f);
      conf_h = fminf(fmaxf(maxp * (1.0f - ent), 0.0f), 1.0f);

      float a0 = e0 * invS, a1 = e1 * invS;
      unsigned long long m = km0;
      while (m) {
        int t = __builtin_ctzll(m);
        acc += __shfl(a0, t, 64) * __bfloat162float(vt[t * 64 + lane]);
        m &= m - 1;
      }
      m = km1;
      while (m) {
        int t = __builtin_ctzll(m);
        acc += __shfl(a1, t, 64) * __bfloat162float(vt[(t + 64) * 64 + lane]);
        m &= m - 1;
      }
    }
    if (lane == 0) confh[(size_t)h * MROWS + b * 4096 + n] = conf_h;
    aligned[qbase + lane] = __float2bfloat16(acc);
  }
}

// ---------------- bf16 MFMA GEMM, m97-style global_load_lds staging ----------------
// C = A(MxK bf16) @ BT^T + bias; BT is NxK bf16. M%128==0, N%128==0, K%32==0.
// mode 0: out bf16; mode 1: out fp32; mode 2: out d_out (fp32 if *flag else bf16) at ooff.
__global__ __launch_bounds__(256) void mfma_gemm(const short* __restrict__ A,
                                                 const short* __restrict__ BT,
                                                 const float* __restrict__ bias,
                                                 void* __restrict__ outp,
                                                 int mode, size_t ooff,
                                                 const int* __restrict__ flag,
                                                 const float* __restrict__ resid,
                                                 int M, int N, int K, int act) {
  __shared__ short As[128 * 32];   // unpadded: required by global_load_lds lane mapping
  __shared__ short Bs[128 * 32];
  int tid = threadIdx.x;
  int lane = tid & 63, w = tid >> 6;
  int wr = w >> 1, wc = w & 1;
  int bm = blockIdx.y * 128, bn = blockIdx.x * 128;
  float4v acc[4][4];
#pragma unroll
  for (int i = 0; i < 4; ++i)
#pragma unroll
    for (int j = 0; j < 4; ++j) acc[i][j] = (float4v){0.f, 0.f, 0.f, 0.f};

  int srow = w * 32 + (lane >> 2);
  int scol = (lane & 3) * 8;
  const short* Ag0 = A + (size_t)(bm + srow) * K + scol;
  const short* Ag1 = A + (size_t)(bm + srow + 16) * K + scol;
  const short* Bg0 = BT + (size_t)(bn + srow) * K + scol;
  const short* Bg1 = BT + (size_t)(bn + srow + 16) * K + scol;
  short* Al0 = As + w * 1024;
  short* Al1 = As + w * 1024 + 512;
  short* Bl0 = Bs + w * 1024;
  short* Bl1 = Bs + w * 1024 + 512;

  int m0 = wr * 64 + (lane & 15);
  int n0 = wc * 64 + (lane & 15);
  int kg = (lane >> 4) * 8;

  for (int k0 = 0; k0 < K; k0 += 32) {
    __syncthreads();
    gload16(Ag0 + k0, Al0);
    gload16(Ag1 + k0, Al1);
    gload16(Bg0 + k0, Bl0);
    gload16(Bg1 + k0, Bl1);
    __syncthreads();
    short8 af[4], bf[4];
#pragma unroll
    for (int mi = 0; mi < 4; ++mi) af[mi] = *(const short8*)&As[(m0 + mi * 16) * 32 + kg];
#pragma unroll
    for (int ni = 0; ni < 4; ++ni) bf[ni] = *(const short8*)&Bs[(n0 + ni * 16) * 32 + kg];
#pragma unroll
    for (int mi = 0; mi < 4; ++mi)
#pragma unroll
      for (int ni = 0; ni < 4; ++ni)
        acc[mi][ni] = __builtin_amdgcn_mfma_f32_16x16x32_bf16(af[mi], bf[ni], acc[mi][ni], 0, 0, 0);
  }

  int outf32 = (mode == 2) ? *flag : 0;
#pragma unroll
  for (int mi = 0; mi < 4; ++mi) {
#pragma unroll
    for (int ni = 0; ni < 4; ++ni) {
#pragma unroll
      for (int r = 0; r < 4; ++r) {
        int gr = bm + wr * 64 + mi * 16 + (lane >> 4) * 4 + r;
        int gc = bn + wc * 64 + ni * 16 + (lane & 15);
        float v = acc[mi][ni][r] + bias[gc];
        if (act == 1) v = 0.5f * v * (1.0f + erff(v * 0.70710678118654752f));
        if (resid) v += resid[(size_t)gr * N + gc];
        size_t oi = (size_t)gr * N + gc;
        if (mode == 0)      ((__hip_bfloat16*)outp)[oi] = __float2bfloat16(v);
        else if (mode == 1) ((float*)outp)[oi] = v;
        else {
          if (outf32) ((float*)outp)[ooff + oi] = v;
          else        ((__hip_bfloat16*)outp)[ooff + oi] = __float2bfloat16(v);
        }
      }
    }
  }
}

// ---------------- fused k & v fp32 GEMM (raw inputs), M=616 ----------------
__global__ __launch_bounds__(256) void kv_gemm(const void* __restrict__ text,
                                               const void* __restrict__ Wk,
                                               const void* __restrict__ Wv,
                                               const float* __restrict__ bk,
                                               const float* __restrict__ bv,
                                               float* __restrict__ kf,
                                               float* __restrict__ vf,
                                               const int* __restrict__ flag) {
  __shared__ float As[16][128];
  __shared__ float Bs[16][128];
  int f = *flag;
  int isv = blockIdx.x >> 2;
  int bn = (blockIdx.x & 3) * 128;
  int bm = blockIdx.y * 128;
  const void* B = isv ? Wv : Wk;
  const float* bias = isv ? bv : bk;
  float* C = isv ? vf : kf;
  int tid = threadIdx.x;
  int tx = tid & 15, ty = tid >> 4;
  float acc[8][8] = {};
  for (int k0 = 0; k0 < 512; k0 += 16) {
#pragma unroll
    for (int r = 0; r < 8; ++r) {
      int idx = tid + r * 256;
      int row = idx >> 4, kk = idx & 15;
      int gr = bm + row;
      As[kk][row] = (gr < BTOK) ? ldin(text, (size_t)gr * 512 + k0 + kk, f) : 0.0f;
    }
#pragma unroll
    for (int r = 0; r < 8; ++r) {
      int idx = tid + r * 256;
      int kk = idx >> 7, col = idx & 127;
      Bs[kk][col] = ldin(B, (size_t)(k0 + kk) * 512 + bn + col, f);
    }
    __syncthreads();
#pragma unroll
    for (int kk = 0; kk < 16; ++kk) {
      float ra[8], rb[8];
#pragma unroll
      for (int i = 0; i < 8; ++i) ra[i] = As[kk][ty * 8 + i];
#pragma unroll
      for (int j = 0; j < 8; ++j) rb[j] = Bs[kk][tx * 8 + j];
#pragma unroll
      for (int i = 0; i < 8; ++i)
#pragma unroll
        for (int j = 0; j < 8; ++j) acc[i][j] += ra[i] * rb[j];
    }
    __syncthreads();
  }
#pragma unroll
  for (int i = 0; i < 8; ++i) {
    int gr = bm + ty * 8 + i;
    if (gr >= BTOK) continue;
#pragma unroll
    for (int j = 0; j < 8; ++j) {
      int gc = bn + tx * 8 + j;
      C[(size_t)gr * 512 + gc] = acc[i][j] + bias[gc];
    }
  }
}

extern "C" void kernel_launch(void* const* d_in, const int* in_sizes, int n_in,
                              void* d_out, int out_size, void* d_ws, size_t ws_size,
                              hipStream_t stream) {
  const void* visual = d_in[0];
  const void* text   = d_in[1];

  char* wsb = (char*)d_ws;
  size_t off = 0;
  auto alloc = [&](size_t bytes) { char* p = wsb + off; off += (bytes + 63) & ~63ull; return p; };

  float* qpy  = (float*)alloc((size_t)NTOK * 4);                    // q -> proj -> y
  __hip_bfloat16* xb2 = (__hip_bfloat16*)alloc((size_t)NTOK * 2);   // x -> y2
  __hip_bfloat16* alb = (__hip_bfloat16*)alloc((size_t)NTOK * 2);   // aligned
  __hip_bfloat16* h1b = (__hip_bfloat16*)alloc((size_t)16384 * 2048 * 2); // MLP hidden (half-M chunk)
  float* kfb  = (float*)alloc((size_t)BTOK * CDIM * 4);
  float* vfb  = (float*)alloc((size_t)BTOK * CDIM * 4);
  float* padb = (float*)alloc(BTOK * 4);
  float* confh = (float*)alloc((size_t)8 * MROWS * 4);
  float* n1w = (float*)alloc(512 * 4);  float* n1b = (float*)alloc(512 * 4);
  float* n2w = (float*)alloc(512 * 4);  float* n2b = (float*)alloc(512 * 4);
  float* bq  = (float*)alloc(512 * 4);  float* bk = (float*)alloc(512 * 4);
  float* bv  = (float*)alloc(512 * 4);  float* bo = (float*)alloc(512 * 4);
  float* Wgf = (float*)alloc(512 * 4);  float* bg = (float*)alloc(16);
  float* lsb = (float*)alloc(16);
  float* b1  = (float*)alloc(2048 * 4); float* b2 = (float*)alloc(512 * 4);
  float* alp = (float*)alloc(16);
  __hip_bfloat16* WqT = (__hip_bfloat16*)alloc((size_t)262144 * 2);
  __hip_bfloat16* WoT = (__hip_bfloat16*)alloc((size_t)262144 * 2);
  __hip_bfloat16* W1T = (__hip_bfloat16*)alloc((size_t)1048576 * 2);
  __hip_bfloat16* W2T = (__hip_bfloat16*)alloc((size_t)1048576 * 2);
  int* flag = (int*)alloc(16);

  detect_kernel<<<1, 256, 0, stream>>>((const unsigned int*)text, flag);

  PCTab tab = {{
    {d_in[2], n1w, 512}, {d_in[3], n1b, 512}, {d_in[4], n2w, 512}, {d_in[5], n2b, 512},
    {d_in[7], bq, 512},  {d_in[9], bk, 512},  {d_in[11], bv, 512}, {d_in[13], bo, 512},
    {d_in[14], Wgf, 512}, {d_in[15], bg, 1},  {d_in[16], lsb, 1},
    {d_in[18], b1, 2048}, {d_in[20], b2, 512}, {d_in[21], alp, 1},
  }};
  cvt_params_kernel<<<14, 256, 0, stream>>>(tab, flag);

  tcvt_kernel<<<dim3(16, 16), 256, 0, stream>>>(d_in[6],  WqT, 512, 512, flag);
  tcvt_kernel<<<dim3(16, 16), 256, 0, stream>>>(d_in[12], WoT, 512, 512, flag);
  tcvt_kernel<<<dim3(64, 16), 256, 0, stream>>>(d_in[17], W1T, 512, 2048, flag);
  tcvt_kernel<<<dim3(16, 64), 256, 0, stream>>>(d_in[19], W2T, 2048, 512, flag);

  pad_kernel<<<BTOK, 256, 0, stream>>>(text, padb, flag);
  ln_kernel<<<MROWS, 256, 0, stream>>>(visual, n1w, n1b, xb2, flag);

  mfma_gemm<<<dim3(4, 256), 256, 0, stream>>>((const short*)xb2, (const short*)WqT, bq,
                                              qpy, 1, 0, flag, nullptr, MROWS, 512, 512, 0);
  kv_gemm<<<dim3(8, 5), 256, 0, stream>>>(text, d_in[8], d_in[10], bk, bv, kfb, vfb, flag);
  rownorm_kernel<<<MROWS, 256, 0, stream>>>(qpy);
  rownorm_kernel<<<BTOK, 256, 0, stream>>>(kfb);

  attn_kernel<<<8 * 8 * 128, 256, 0, stream>>>(qpy, kfb, vfb, padb, lsb, alb, confh);

  mfma_gemm<<<dim3(4, 256), 256, 0, stream>>>((const short*)alb, (const short*)WoT, bo,
                                              qpy, 1, 0, flag, nullptr, MROWS, 512, 512, 0);
  combine_ln_kernel<<<MROWS, 256, 0, stream>>>(xb2, qpy, confh, Wgf, bg, alp, n2w, n2b, xb2);

  // MLP in 2 chunks of 16384 rows
  for (int c = 0; c < 2; ++c) {
    const short* ychunk = (const short*)(xb2 + (size_t)c * 16384 * CDIM);
    const float* yres   = qpy + (size_t)c * 16384 * CDIM;
    mfma_gemm<<<dim3(16, 128), 256, 0, stream>>>(ychunk, (const short*)W1T, b1,
                                                 h1b, 0, 0, flag, nullptr, 16384, 2048, 512, 1);
    mfma_gemm<<<dim3(4, 128), 256, 0, stream>>>((const short*)h1b, (const short*)W2T, b2,
                                                d_out, 2, (size_t)c * 16384 * CDIM, flag, yres,
                                                16384, 512, 2048, 0);
  }
}

// Round 5
// 1125.628 us; speedup vs baseline: 1.0953x; 1.0953x over previous
//
#include <hip/hip_runtime.h>
#include <hip/hip_bf16.h>
#include <math.h>

// B=8, H=64, W=64, C=512 -> rows M = 32768; T=77, HH=8, DH=64, TOP_M=3
#define MROWS 32768
#define CDIM  512
#define TTOK  77
#define BTOK  616
#define NTOK  16777216

typedef __attribute__((ext_vector_type(8))) short short8;
typedef __attribute__((ext_vector_type(4))) float float4v;

__device__ __forceinline__ float ldin(const void* p, size_t i, int isf32) {
  return isf32 ? ((const float*)p)[i]
               : __bfloat162float(((const __hip_bfloat16*)p)[i]);
}

// async global->LDS, 16B per lane; LDS dest = uniform base + lane*16
__device__ __forceinline__ void gload16(const void* g, void* l) {
  __builtin_amdgcn_global_load_lds((const __attribute__((address_space(1))) unsigned int*)g,
                                   (__attribute__((address_space(3))) unsigned int*)l,
                                   16, 0, 0);
}

__device__ __forceinline__ float wave_sum(float v) {
#pragma unroll
  for (int off = 32; off > 0; off >>= 1) v += __shfl_xor(v, off, 64);
  return v;
}
__device__ __forceinline__ float wave_max(float v) {
#pragma unroll
  for (int off = 32; off > 0; off >>= 1) v = fmaxf(v, __shfl_xor(v, off, 64));
  return v;
}
__device__ __forceinline__ float block_sum256(float v) {
  __shared__ float red[4];
  int lane = threadIdx.x & 63, wid = threadIdx.x >> 6;
  float s = wave_sum(v);
  if (lane == 0) red[wid] = s;
  __syncthreads();
  s = red[0] + red[1] + red[2] + red[3];
  __syncthreads();
  return s;
}

// dtype detect (proven): 1 => fp32 inputs, 0 => bf16 inputs
__global__ __launch_bounds__(256) void detect_kernel(const unsigned int* __restrict__ t,
                                                     int* __restrict__ flag) {
  int insane = 0;
  for (int i = threadIdx.x; i < 4096; i += 256) {
    unsigned int lo = t[i] & 0xFFFFu;
    int e = (int)((lo >> 7) & 0xFFu);
    int sane = (lo == 0u) || (e >= 87 && e <= 147);
    insane += 1 - sane;
  }
  float tot = block_sum256((float)insane);
  if (threadIdx.x == 0) flag[0] = (tot > 1024.0f) ? 1 : 0;
}

// fused small-parameter convert: one block per segment
struct PC { const void* src; float* dst; int n; };
struct PCTab { PC e[14]; };
__global__ __launch_bounds__(256) void cvt_params_kernel(PCTab t, const int* __restrict__ flag) {
  int f = *flag;
  PC p = t.e[blockIdx.x];
  for (int i = threadIdx.x; i < p.n; i += 256) p.dst[i] = ldin(p.src, i, f);
}

// weight transpose+convert: in (KxN, raw dtype) -> out bf16 (NxK)
__global__ __launch_bounds__(256) void tcvt_kernel(const void* __restrict__ in,
                                                   __hip_bfloat16* __restrict__ out,
                                                   int K, int N, const int* __restrict__ flag) {
  __shared__ float tile[32][33];
  int tx = threadIdx.x & 31, ty = threadIdx.x >> 5;   // 32 x 8
  int k0 = blockIdx.y * 32, n0 = blockIdx.x * 32;
  int f = *flag;
#pragma unroll
  for (int r = 0; r < 4; ++r) {
    int k = k0 + ty + r * 8;
    tile[ty + r * 8][tx] = ldin(in, (size_t)k * N + n0 + tx, f);
  }
  __syncthreads();
#pragma unroll
  for (int r = 0; r < 4; ++r) {
    int n = n0 + ty + r * 8;
    out[(size_t)n * K + k0 + tx] = __float2bfloat16(tile[tx][ty + r * 8]);
  }
}

// pad mask straight from raw text
__global__ __launch_bounds__(256) void pad_kernel(const void* __restrict__ text,
                                                  float* __restrict__ pad,
                                                  const int* __restrict__ flag) {
  int row = blockIdx.x;
  size_t base = (size_t)row * CDIM;
  int tid = threadIdx.x;
  int f = *flag;
  float s = fabsf(ldin(text, base + tid, f)) + fabsf(ldin(text, base + 256 + tid, f));
  float tot = block_sum256(s);
  if (tid == 0) pad[row] = (tot <= 1e-6f) ? 1.0f : 0.0f;
}

// LayerNorm over C=512 (raw flag-dtype input) -> bf16 out
__global__ __launch_bounds__(256) void ln_kernel(const void* __restrict__ in,
                                                 const float* __restrict__ w,
                                                 const float* __restrict__ b,
                                                 __hip_bfloat16* __restrict__ out,
                                                 const int* __restrict__ flag) {
  int row = blockIdx.x;
  size_t base = (size_t)row * CDIM;
  int tid = threadIdx.x;
  int f = *flag;
  float v0 = ldin(in, base + tid, f);
  float v1 = ldin(in, base + 256 + tid, f);
  float tot = block_sum256(v0 + v1);
  float mu = tot * (1.0f / 512.0f);
  float d0 = v0 - mu, d1 = v1 - mu;
  float rs = rsqrtf(block_sum256(d0 * d0 + d1 * d1) * (1.0f / 512.0f) + 1e-5f);
  out[base + tid]       = __float2bfloat16(d0 * rs * w[tid]       + b[tid]);
  out[base + 256 + tid] = __float2bfloat16(d1 * rs * w[256 + tid] + b[256 + tid]);
}

__global__ __launch_bounds__(256) void rownorm_kernel(float* __restrict__ x) {
  int row = blockIdx.x;
  size_t base = (size_t)row * CDIM;
  int tid = threadIdx.x;
  float v0 = x[base + tid], v1 = x[base + 256 + tid];
  float sq = block_sum256(v0 * v0 + v1 * v1);
  float inv = 1.0f / fmaxf(sqrtf(sq), 1e-6f);
  x[base + tid] = v0 * inv;
  x[base + 256 + tid] = v1 * inv;
}

// fused gate + combine + LN2:
//   g   = alpha * sigmoid(x.Wg + bg) * (mean_h conf >= 0.35)
//   y   = x + g*proj   (fp32 back into proj, needed as MLP residual)
//   y2  = LN(y) -> bf16
__global__ __launch_bounds__(256) void combine_ln_kernel(const __hip_bfloat16* __restrict__ x,
                                                         float* __restrict__ proj,
                                                         const float* __restrict__ confh,
                                                         const float* __restrict__ Wg,
                                                         const float* __restrict__ bg,
                                                         const float* __restrict__ alpha_p,
                                                         const float* __restrict__ w,
                                                         const float* __restrict__ b,
                                                         __hip_bfloat16* __restrict__ y2) {
  int row = blockIdx.x;
  size_t base = (size_t)row * CDIM;
  int tid = threadIdx.x;
  float xv0 = __bfloat162float(x[base + tid]);
  float xv1 = __bfloat162float(x[base + 256 + tid]);
  float dot = block_sum256(xv0 * Wg[tid] + xv1 * Wg[256 + tid]);
  float csp = (tid < 8) ? confh[(size_t)tid * MROWS + row] : 0.0f;
  float cs = block_sum256(csp);
  float gate = 1.0f / (1.0f + __expf(-(dot + bg[0])));
  float byp = (cs * 0.125f >= 0.35f) ? 1.0f : 0.0f;
  float gv = alpha_p[0] * gate * byp;

  float v0 = xv0 + gv * proj[base + tid];
  float v1 = xv1 + gv * proj[base + 256 + tid];
  proj[base + tid] = v0;
  proj[base + 256 + tid] = v1;
  float tot = block_sum256(v0 + v1);
  float mu = tot * (1.0f / 512.0f);
  float d0 = v0 - mu, d1 = v1 - mu;
  float rs = rsqrtf(block_sum256(d0 * d0 + d1 * d1) * (1.0f / 512.0f) + 1e-5f);
  y2[base + tid]       = __float2bfloat16(d0 * rs * w[tid]       + b[tid]);
  y2[base + 256 + tid] = __float2bfloat16(d1 * rs * w[256 + tid] + b[256 + tid]);
}

// ---------------- attention (r3 structure + fast transcendentals) ----------------
// Round-4 post-mortem: K register-blocking (fewer LDS reads) REGRESSED 251->352us:
// VGPR 84->120, long dep regions, occupancy 33.8->22.9, VALUBusy 64.7->48.7 with
// VALU busy-time ~constant -> r3 is VALU-issue-bound, not LDS-bound. So: keep r3's
// exact loop shape (best-scheduled variant) and cut VALU instead: __expf/__logf
// (hw v_exp/v_log) replace libm expf/logf (~20+ instrs each). scale perturbation
// multiplies all logits uniformly -> top-3 selection ordering exactly invariant.
// LDS 39424B -> 4 blocks/CU. No forced waves-per-EU cap (round-1 spill lesson).
__global__ __launch_bounds__(256) void attn_kernel(const float* __restrict__ qn,
                                                   const float* __restrict__ kn,
                                                   const float* __restrict__ vf,
                                                   const float* __restrict__ pad,
                                                   const float* __restrict__ ls_p,
                                                   __hip_bfloat16* __restrict__ aligned,
                                                   float* __restrict__ confh) {
  __shared__ float kt[TTOK * 68];
  __shared__ __hip_bfloat16 vt[TTOK * 64];
  __shared__ float qt[32 * 64];
  int tid = threadIdx.x;
  int lane = tid & 63, wid = tid >> 6;
  int blk = blockIdx.x;
  int nchunk = blk & 127;
  int bh = blk >> 7;
  int h = bh & 7, b = bh >> 3;

  for (int idx = tid; idx < TTOK * 64; idx += 256) {
    int t = idx >> 6, d = idx & 63;
    size_t src = ((size_t)(b * TTOK + t)) * CDIM + h * 64 + d;
    kt[t * 68 + d] = kn[src];
    vt[t * 64 + d] = __float2bfloat16(vf[src]);
  }
  for (int idx = tid; idx < 32 * 64; idx += 256) {
    int nl = idx >> 6, d = idx & 63;
    qt[idx] = qn[((size_t)(b * 4096 + nchunk * 32 + nl)) * CDIM + h * 64 + d];
  }
  __syncthreads();

  float ls = fminf(fmaxf(ls_p[0], -2.0f), 2.0f);
  float scale = __expf(ls) * 0.125f;
  const float NEGINF = -__builtin_inff();
  float pv0 = pad[b * TTOK + lane];
  int t1ok = (lane + 64 < TTOK);
  float pv1 = t1ok ? pad[b * TTOK + lane + 64] : 1.0f;
  int t1 = t1ok ? lane + 64 : 0;

  for (int i = 0; i < 8; ++i) {
    int nl = wid * 8 + i;
    int n = nchunk * 32 + nl;
    size_t qbase = ((size_t)(b * 4096 + n)) * CDIM + h * 64;
    float s0 = 0.0f, s1 = 0.0f;
    const float4* qv4 = (const float4*)&qt[nl * 64];
    const float4* k0p = (const float4*)&kt[lane * 68];
    const float4* k1p = (const float4*)&kt[t1 * 68];
#pragma unroll
    for (int dg = 0; dg < 16; ++dg) {
      float4 qq = qv4[dg];
      float4 ka = k0p[dg];
      float4 kb = k1p[dg];
      s0 += qq.x * ka.x + qq.y * ka.y + qq.z * ka.z + qq.w * ka.w;
      s1 += qq.x * kb.x + qq.y * kb.y + qq.z * kb.z + qq.w * kb.w;
    }
    float v0 = (pv0 > 0.0f) ? NEGINF : s0 * scale;
    float v1 = (!t1ok || pv1 > 0.0f) ? NEGINF : s1 * scale;

    float m1 = wave_max(fmaxf(v0, v1));
    float acc = 0.0f, conf_h = 0.0f;
    if (m1 != NEGINF) {
      // top-3 threshold (identical logic/order to proven version)
      int c1 = __popcll(__ballot(v0 >= m1)) + __popcll(__ballot(v1 >= m1));
      float thr;
      if (c1 >= 3) thr = m1;
      else {
        float m2 = wave_max(fmaxf(v0 < m1 ? v0 : NEGINF, v1 < m1 ? v1 : NEGINF));
        int c2 = __popcll(__ballot(v0 >= m2)) + __popcll(__ballot(v1 >= m2));
        if (c2 >= 3) thr = m2;
        else thr = wave_max(fmaxf(v0 < m2 ? v0 : NEGINF, v1 < m2 ? v1 : NEGINF));
      }
      bool kp0 = (v0 >= thr) && (v0 != NEGINF);
      bool kp1 = (v1 >= thr) && (v1 != NEGINF);
      float d0 = v0 - m1, d1 = v1 - m1;
      float e0 = kp0 ? __expf(d0) : 0.0f;
      float e1 = kp1 ? __expf(d1) : 0.0f;
      // fused pair reduction: S1 = sum e, S2 = sum e*(v-m1)
      float S1 = e0 + e1;
      float S2 = e0 * d0 + e1 * d1;
#pragma unroll
      for (int off = 32; off > 0; off >>= 1) {
        S1 += __shfl_xor(S1, off, 64);
        S2 += __shfl_xor(S2, off, 64);
      }
      unsigned long long km0 = __ballot(kp0);
      unsigned long long km1 = __ballot(kp1);
      int cnt = __popcll(km0) + __popcll(km1);
      float invS = 1.0f / S1;
      float maxp = invS;                       // max prob = exp(0)/S1
      // -sum p ln p = ln S1 - S2/S1 ; plus reference's 1e-8 clamp terms for zeros
      float es = (__logf(S1) - S2 * invS) + (float)(TTOK - cnt) * 1.8420680743952367e-7f;
      float teff = fmaxf((float)cnt, 2.0f);
      float ent = fmaxf(es / __logf(teff), 0.0f);
      conf_h = fminf(fmaxf(maxp * (1.0f - ent), 0.0f), 1.0f);

      float a0 = e0 * invS, a1 = e1 * invS;
      unsigned long long m = km0;
      while (m) {
        int t = __builtin_ctzll(m);
        acc += __shfl(a0, t, 64) * __bfloat162float(vt[t * 64 + lane]);
        m &= m - 1;
      }
      m = km1;
      while (m) {
        int t = __builtin_ctzll(m);
        acc += __shfl(a1, t, 64) * __bfloat162float(vt[(t + 64) * 64 + lane]);
        m &= m - 1;
      }
    }
    if (lane == 0) confh[(size_t)h * MROWS + b * 4096 + n] = conf_h;
    aligned[qbase + lane] = __float2bfloat16(acc);
  }
}

// ---------------- bf16 MFMA GEMM, m97-style global_load_lds staging ----------------
// C = A(MxK bf16) @ BT^T + bias; BT is NxK bf16. M%128==0, N%128==0, K%32==0.
// mode 0: out bf16; mode 1: out fp32; mode 2: out d_out (fp32 if *flag else bf16) at ooff.
__global__ __launch_bounds__(256) void mfma_gemm(const short* __restrict__ A,
                                                 const short* __restrict__ BT,
                                                 const float* __restrict__ bias,
                                                 void* __restrict__ outp,
                                                 int mode, size_t ooff,
                                                 const int* __restrict__ flag,
                                                 const float* __restrict__ resid,
                                                 int M, int N, int K, int act) {
  __shared__ short As[128 * 32];   // unpadded: required by global_load_lds lane mapping
  __shared__ short Bs[128 * 32];
  int tid = threadIdx.x;
  int lane = tid & 63, w = tid >> 6;
  int wr = w >> 1, wc = w & 1;
  int bm = blockIdx.y * 128, bn = blockIdx.x * 128;
  float4v acc[4][4];
#pragma unroll
  for (int i = 0; i < 4; ++i)
#pragma unroll
    for (int j = 0; j < 4; ++j) acc[i][j] = (float4v){0.f, 0.f, 0.f, 0.f};

  int srow = w * 32 + (lane >> 2);
  int scol = (lane & 3) * 8;
  const short* Ag0 = A + (size_t)(bm + srow) * K + scol;
  const short* Ag1 = A + (size_t)(bm + srow + 16) * K + scol;
  const short* Bg0 = BT + (size_t)(bn + srow) * K + scol;
  const short* Bg1 = BT + (size_t)(bn + srow + 16) * K + scol;
  short* Al0 = As + w * 1024;
  short* Al1 = As + w * 1024 + 512;
  short* Bl0 = Bs + w * 1024;
  short* Bl1 = Bs + w * 1024 + 512;

  int m0 = wr * 64 + (lane & 15);
  int n0 = wc * 64 + (lane & 15);
  int kg = (lane >> 4) * 8;

  for (int k0 = 0; k0 < K; k0 += 32) {
    __syncthreads();
    gload16(Ag0 + k0, Al0);
    gload16(Ag1 + k0, Al1);
    gload16(Bg0 + k0, Bl0);
    gload16(Bg1 + k0, Bl1);
    __syncthreads();
    short8 af[4], bf[4];
#pragma unroll
    for (int mi = 0; mi < 4; ++mi) af[mi] = *(const short8*)&As[(m0 + mi * 16) * 32 + kg];
#pragma unroll
    for (int ni = 0; ni < 4; ++ni) bf[ni] = *(const short8*)&Bs[(n0 + ni * 16) * 32 + kg];
#pragma unroll
    for (int mi = 0; mi < 4; ++mi)
#pragma unroll
      for (int ni = 0; ni < 4; ++ni)
        acc[mi][ni] = __builtin_amdgcn_mfma_f32_16x16x32_bf16(af[mi], bf[ni], acc[mi][ni], 0, 0, 0);
  }

  int outf32 = (mode == 2) ? *flag : 0;
#pragma unroll
  for (int mi = 0; mi < 4; ++mi) {
#pragma unroll
    for (int ni = 0; ni < 4; ++ni) {
#pragma unroll
      for (int r = 0; r < 4; ++r) {
        int gr = bm + wr * 64 + mi * 16 + (lane >> 4) * 4 + r;
        int gc = bn + wc * 64 + ni * 16 + (lane & 15);
        float v = acc[mi][ni][r] + bias[gc];
        if (act == 1) v = 0.5f * v * (1.0f + erff(v * 0.70710678118654752f));
        if (resid) v += resid[(size_t)gr * N + gc];
        size_t oi = (size_t)gr * N + gc;
        if (mode == 0)      ((__hip_bfloat16*)outp)[oi] = __float2bfloat16(v);
        else if (mode == 1) ((float*)outp)[oi] = v;
        else {
          if (outf32) ((float*)outp)[ooff + oi] = v;
          else        ((__hip_bfloat16*)outp)[ooff + oi] = __float2bfloat16(v);
        }
      }
    }
  }
}

// ---------------- fused k & v fp32 GEMM (raw inputs), M=616 ----------------
__global__ __launch_bounds__(256) void kv_gemm(const void* __restrict__ text,
                                               const void* __restrict__ Wk,
                                               const void* __restrict__ Wv,
                                               const float* __restrict__ bk,
                                               const float* __restrict__ bv,
                                               float* __restrict__ kf,
                                               float* __restrict__ vf,
                                               const int* __restrict__ flag) {
  __shared__ float As[16][128];
  __shared__ float Bs[16][128];
  int f = *flag;
  int isv = blockIdx.x >> 2;
  int bn = (blockIdx.x & 3) * 128;
  int bm = blockIdx.y * 128;
  const void* B = isv ? Wv : Wk;
  const float* bias = isv ? bv : bk;
  float* C = isv ? vf : kf;
  int tid = threadIdx.x;
  int tx = tid & 15, ty = tid >> 4;
  float acc[8][8] = {};
  for (int k0 = 0; k0 < 512; k0 += 16) {
#pragma unroll
    for (int r = 0; r < 8; ++r) {
      int idx = tid + r * 256;
      int row = idx >> 4, kk = idx & 15;
      int gr = bm + row;
      As[kk][row] = (gr < BTOK) ? ldin(text, (size_t)gr * 512 + k0 + kk, f) : 0.0f;
    }
#pragma unroll
    for (int r = 0; r < 8; ++r) {
      int idx = tid + r * 256;
      int kk = idx >> 7, col = idx & 127;
      Bs[kk][col] = ldin(B, (size_t)(k0 + kk) * 512 + bn + col, f);
    }
    __syncthreads();
#pragma unroll
    for (int kk = 0; kk < 16; ++kk) {
      float ra[8], rb[8];
#pragma unroll
      for (int i = 0; i < 8; ++i) ra[i] = As[kk][ty * 8 + i];
#pragma unroll
      for (int j = 0; j < 8; ++j) rb[j] = Bs[kk][tx * 8 + j];
#pragma unroll
      for (int i = 0; i < 8; ++i)
#pragma unroll
        for (int j = 0; j < 8; ++j) acc[i][j] += ra[i] * rb[j];
    }
    __syncthreads();
  }
#pragma unroll
  for (int i = 0; i < 8; ++i) {
    int gr = bm + ty * 8 + i;
    if (gr >= BTOK) continue;
#pragma unroll
    for (int j = 0; j < 8; ++j) {
      int gc = bn + tx * 8 + j;
      C[(size_t)gr * 512 + gc] = acc[i][j] + bias[gc];
    }
  }
}

extern "C" void kernel_launch(void* const* d_in, const int* in_sizes, int n_in,
                              void* d_out, int out_size, void* d_ws, size_t ws_size,
                              hipStream_t stream) {
  const void* visual = d_in[0];
  const void* text   = d_in[1];

  char* wsb = (char*)d_ws;
  size_t off = 0;
  auto alloc = [&](size_t bytes) { char* p = wsb + off; off += (bytes + 63) & ~63ull; return p; };

  float* qpy  = (float*)alloc((size_t)NTOK * 4);                    // q -> proj -> y
  __hip_bfloat16* xb2 = (__hip_bfloat16*)alloc((size_t)NTOK * 2);   // x -> y2
  __hip_bfloat16* alb = (__hip_bfloat16*)alloc((size_t)NTOK * 2);   // aligned
  __hip_bfloat16* h1b = (__hip_bfloat16*)alloc((size_t)16384 * 2048 * 2); // MLP hidden (half-M chunk)
  float* kfb  = (float*)alloc((size_t)BTOK * CDIM * 4);
  float* vfb  = (float*)alloc((size_t)BTOK * CDIM * 4);
  float* padb = (float*)alloc(BTOK * 4);
  float* confh = (float*)alloc((size_t)8 * MROWS * 4);
  float* n1w = (float*)alloc(512 * 4);  float* n1b = (float*)alloc(512 * 4);
  float* n2w = (float*)alloc(512 * 4);  float* n2b = (float*)alloc(512 * 4);
  float* bq  = (float*)alloc(512 * 4);  float* bk = (float*)alloc(512 * 4);
  float* bv  = (float*)alloc(512 * 4);  float* bo = (float*)alloc(512 * 4);
  float* Wgf = (float*)alloc(512 * 4);  float* bg = (float*)alloc(16);
  float* lsb = (float*)alloc(16);
  float* b1  = (float*)alloc(2048 * 4); float* b2 = (float*)alloc(512 * 4);
  float* alp = (float*)alloc(16);
  __hip_bfloat16* WqT = (__hip_bfloat16*)alloc((size_t)262144 * 2);
  __hip_bfloat16* WoT = (__hip_bfloat16*)alloc((size_t)262144 * 2);
  __hip_bfloat16* W1T = (__hip_bfloat16*)alloc((size_t)1048576 * 2);
  __hip_bfloat16* W2T = (__hip_bfloat16*)alloc((size_t)1048576 * 2);
  int* flag = (int*)alloc(16);

  detect_kernel<<<1, 256, 0, stream>>>((const unsigned int*)text, flag);

  PCTab tab = {{
    {d_in[2], n1w, 512}, {d_in[3], n1b, 512}, {d_in[4], n2w, 512}, {d_in[5], n2b, 512},
    {d_in[7], bq, 512},  {d_in[9], bk, 512},  {d_in[11], bv, 512}, {d_in[13], bo, 512},
    {d_in[14], Wgf, 512}, {d_in[15], bg, 1},  {d_in[16], lsb, 1},
    {d_in[18], b1, 2048}, {d_in[20], b2, 512}, {d_in[21], alp, 1},
  }};
  cvt_params_kernel<<<14, 256, 0, stream>>>(tab, flag);

  tcvt_kernel<<<dim3(16, 16), 256, 0, stream>>>(d_in[6],  WqT, 512, 512, flag);
  tcvt_kernel<<<dim3(16, 16), 256, 0, stream>>>(d_in[12], WoT, 512, 512, flag);
  tcvt_kernel<<<dim3(64, 16), 256, 0, stream>>>(d_in[17], W1T, 512, 2048, flag);
  tcvt_kernel<<<dim3(16, 64), 256, 0, stream>>>(d_in[19], W2T, 2048, 512, flag);

  pad_kernel<<<BTOK, 256, 0, stream>>>(text, padb, flag);
  ln_kernel<<<MROWS, 256, 0, stream>>>(visual, n1w, n1b, xb2, flag);

  mfma_gemm<<<dim3(4, 256), 256, 0, stream>>>((const short*)xb2, (const short*)WqT, bq,
                                              qpy, 1, 0, flag, nullptr, MROWS, 512, 512, 0);
  kv_gemm<<<dim3(8, 5), 256, 0, stream>>>(text, d_in[8], d_in[10], bk, bv, kfb, vfb, flag);
  rownorm_kernel<<<MROWS, 256, 0, stream>>>(qpy);
  rownorm_kernel<<<BTOK, 256, 0, stream>>>(kfb);

  attn_kernel<<<8 * 8 * 128, 256, 0, stream>>>(qpy, kfb, vfb, padb, lsb, alb, confh);

  mfma_gemm<<<dim3(4, 256), 256, 0, stream>>>((const short*)alb, (const short*)WoT, bo,
                                              qpy, 1, 0, flag, nullptr, MROWS, 512, 512, 0);
  combine_ln_kernel<<<MROWS, 256, 0, stream>>>(xb2, qpy, confh, Wgf, bg, alp, n2w, n2b, xb2);

  // MLP in 2 chunks of 16384 rows
  for (int c = 0; c < 2; ++c) {
    const short* ychunk = (const short*)(xb2 + (size_t)c * 16384 * CDIM);
    const float* yres   = qpy + (size_t)c * 16384 * CDIM;
    mfma_gemm<<<dim3(16, 128), 256, 0, stream>>>(ychunk, (const short*)W1T, b1,
                                                 h1b, 0, 0, flag, nullptr, 16384, 2048, 512, 1);
    mfma_gemm<<<dim3(4, 128), 256, 0, stream>>>((const short*)h1b, (const short*)W2T, b2,
                                                d_out, 2, (size_t)c * 16384 * CDIM, flag, yres,
                                                16384, 512, 2048, 0);
  }
}

// Round 6
// 1105.177 us; speedup vs baseline: 1.1156x; 1.0185x over previous
//
#include <hip/hip_runtime.h>
#include <hip/hip_bf16.h>
#include <math.h>

// B=8, H=64, W=64, C=512 -> rows M = 32768; T=77, HH=8, DH=64, TOP_M=3
#define MROWS 32768
#define CDIM  512
#define TTOK  77
#define BTOK  616
#define NTOK  16777216

typedef __attribute__((ext_vector_type(8))) short short8;
typedef __attribute__((ext_vector_type(4))) float float4v;

__device__ __forceinline__ float ldin(const void* p, size_t i, int isf32) {
  return isf32 ? ((const float*)p)[i]
               : __bfloat162float(((const __hip_bfloat16*)p)[i]);
}

// async global->LDS, 16B per lane; LDS dest = uniform base + lane*16
__device__ __forceinline__ void gload16(const void* g, void* l) {
  __builtin_amdgcn_global_load_lds((const __attribute__((address_space(1))) unsigned int*)g,
                                   (__attribute__((address_space(3))) unsigned int*)l,
                                   16, 0, 0);
}

__device__ __forceinline__ float wave_sum(float v) {
#pragma unroll
  for (int off = 32; off > 0; off >>= 1) v += __shfl_xor(v, off, 64);
  return v;
}
__device__ __forceinline__ float wave_max(float v) {
#pragma unroll
  for (int off = 32; off > 0; off >>= 1) v = fmaxf(v, __shfl_xor(v, off, 64));
  return v;
}
__device__ __forceinline__ float block_sum256(float v) {
  __shared__ float red[4];
  int lane = threadIdx.x & 63, wid = threadIdx.x >> 6;
  float s = wave_sum(v);
  if (lane == 0) red[wid] = s;
  __syncthreads();
  s = red[0] + red[1] + red[2] + red[3];
  __syncthreads();
  return s;
}

// dtype detect (proven): 1 => fp32 inputs, 0 => bf16 inputs
__global__ __launch_bounds__(256) void detect_kernel(const unsigned int* __restrict__ t,
                                                     int* __restrict__ flag) {
  int insane = 0;
  for (int i = threadIdx.x; i < 4096; i += 256) {
    unsigned int lo = t[i] & 0xFFFFu;
    int e = (int)((lo >> 7) & 0xFFu);
    int sane = (lo == 0u) || (e >= 87 && e <= 147);
    insane += 1 - sane;
  }
  float tot = block_sum256((float)insane);
  if (threadIdx.x == 0) flag[0] = (tot > 1024.0f) ? 1 : 0;
}

// fused small-parameter convert: one block per segment
struct PC { const void* src; float* dst; int n; };
struct PCTab { PC e[14]; };
__global__ __launch_bounds__(256) void cvt_params_kernel(PCTab t, const int* __restrict__ flag) {
  int f = *flag;
  PC p = t.e[blockIdx.x];
  for (int i = threadIdx.x; i < p.n; i += 256) p.dst[i] = ldin(p.src, i, f);
}

// weight transpose+convert: in (KxN, raw dtype) -> out bf16 (NxK)
__global__ __launch_bounds__(256) void tcvt_kernel(const void* __restrict__ in,
                                                   __hip_bfloat16* __restrict__ out,
                                                   int K, int N, const int* __restrict__ flag) {
  __shared__ float tile[32][33];
  int tx = threadIdx.x & 31, ty = threadIdx.x >> 5;   // 32 x 8
  int k0 = blockIdx.y * 32, n0 = blockIdx.x * 32;
  int f = *flag;
#pragma unroll
  for (int r = 0; r < 4; ++r) {
    int k = k0 + ty + r * 8;
    tile[ty + r * 8][tx] = ldin(in, (size_t)k * N + n0 + tx, f);
  }
  __syncthreads();
#pragma unroll
  for (int r = 0; r < 4; ++r) {
    int n = n0 + ty + r * 8;
    out[(size_t)n * K + k0 + tx] = __float2bfloat16(tile[tx][ty + r * 8]);
  }
}

// pad mask straight from raw text
__global__ __launch_bounds__(256) void pad_kernel(const void* __restrict__ text,
                                                  float* __restrict__ pad,
                                                  const int* __restrict__ flag) {
  int row = blockIdx.x;
  size_t base = (size_t)row * CDIM;
  int tid = threadIdx.x;
  int f = *flag;
  float s = fabsf(ldin(text, base + tid, f)) + fabsf(ldin(text, base + 256 + tid, f));
  float tot = block_sum256(s);
  if (tid == 0) pad[row] = (tot <= 1e-6f) ? 1.0f : 0.0f;
}

// LayerNorm over C=512 (raw flag-dtype input) -> bf16 out
__global__ __launch_bounds__(256) void ln_kernel(const void* __restrict__ in,
                                                 const float* __restrict__ w,
                                                 const float* __restrict__ b,
                                                 __hip_bfloat16* __restrict__ out,
                                                 const int* __restrict__ flag) {
  int row = blockIdx.x;
  size_t base = (size_t)row * CDIM;
  int tid = threadIdx.x;
  int f = *flag;
  float v0 = ldin(in, base + tid, f);
  float v1 = ldin(in, base + 256 + tid, f);
  float tot = block_sum256(v0 + v1);
  float mu = tot * (1.0f / 512.0f);
  float d0 = v0 - mu, d1 = v1 - mu;
  float rs = rsqrtf(block_sum256(d0 * d0 + d1 * d1) * (1.0f / 512.0f) + 1e-5f);
  out[base + tid]       = __float2bfloat16(d0 * rs * w[tid]       + b[tid]);
  out[base + 256 + tid] = __float2bfloat16(d1 * rs * w[256 + tid] + b[256 + tid]);
}

__global__ __launch_bounds__(256) void rownorm_kernel(float* __restrict__ x) {
  int row = blockIdx.x;
  size_t base = (size_t)row * CDIM;
  int tid = threadIdx.x;
  float v0 = x[base + tid], v1 = x[base + 256 + tid];
  float sq = block_sum256(v0 * v0 + v1 * v1);
  float inv = 1.0f / fmaxf(sqrtf(sq), 1e-6f);
  x[base + tid] = v0 * inv;
  x[base + 256 + tid] = v1 * inv;
}

// fused gate + combine + LN2:
//   g   = alpha * sigmoid(x.Wg + bg) * (mean_h conf >= 0.35)
//   y   = x + g*proj   (fp32 back into proj, needed as MLP residual)
//   y2  = LN(y) -> bf16
__global__ __launch_bounds__(256) void combine_ln_kernel(const __hip_bfloat16* __restrict__ x,
                                                         float* __restrict__ proj,
                                                         const float* __restrict__ confh,
                                                         const float* __restrict__ Wg,
                                                         const float* __restrict__ bg,
                                                         const float* __restrict__ alpha_p,
                                                         const float* __restrict__ w,
                                                         const float* __restrict__ b,
                                                         __hip_bfloat16* __restrict__ y2) {
  int row = blockIdx.x;
  size_t base = (size_t)row * CDIM;
  int tid = threadIdx.x;
  float xv0 = __bfloat162float(x[base + tid]);
  float xv1 = __bfloat162float(x[base + 256 + tid]);
  float dot = block_sum256(xv0 * Wg[tid] + xv1 * Wg[256 + tid]);
  float csp = (tid < 8) ? confh[(size_t)tid * MROWS + row] : 0.0f;
  float cs = block_sum256(csp);
  float gate = 1.0f / (1.0f + __expf(-(dot + bg[0])));
  float byp = (cs * 0.125f >= 0.35f) ? 1.0f : 0.0f;
  float gv = alpha_p[0] * gate * byp;

  float v0 = xv0 + gv * proj[base + tid];
  float v1 = xv1 + gv * proj[base + 256 + tid];
  proj[base + tid] = v0;
  proj[base + 256 + tid] = v1;
  float tot = block_sum256(v0 + v1);
  float mu = tot * (1.0f / 512.0f);
  float d0 = v0 - mu, d1 = v1 - mu;
  float rs = rsqrtf(block_sum256(d0 * d0 + d1 * d1) * (1.0f / 512.0f) + 1e-5f);
  y2[base + tid]       = __float2bfloat16(d0 * rs * w[tid]       + b[tid]);
  y2[base + 256 + tid] = __float2bfloat16(d1 * rs * w[256 + tid] + b[256 + tid]);
}

// ---------------- attention (r5 structure + single-chain top3 + closed-form S) ----
// Round-5 post-mortem: __expf helped only 10us -> the stall is the 4 dependent
// cross-lane chains per row (~30 serial ds_swizzle @ ~30cyc). This round:
//  (a) ONE 6-step shfl_xor butterfly merges per-lane sorted pairs into the global
//      top-3 triple (r1>=r2>=r3, pure max/min -> exact, multiset semantics:
//      r3 == reference topv[-1], r1 == m1 bit-exact; selection unchanged).
//  (b) kept multiset == {r1, r2, (cnt-2) copies of r3}  (cnt from PV ballots), so
//      S1 = 1 + e^{d2} + (cnt-2)e^{d3}, S2 = d2 e^{d2} + (cnt-2) d3 e^{d3}
//      -> the 12-shfl S-reduction is deleted. NEGINF-guarded for <3 valid tokens.
// QK loop / staging / PV bit-loop untouched (r4 lesson). LDS 39424B, 4 blocks/CU.
__global__ __launch_bounds__(256) void attn_kernel(const float* __restrict__ qn,
                                                   const float* __restrict__ kn,
                                                   const float* __restrict__ vf,
                                                   const float* __restrict__ pad,
                                                   const float* __restrict__ ls_p,
                                                   __hip_bfloat16* __restrict__ aligned,
                                                   float* __restrict__ confh) {
  __shared__ float kt[TTOK * 68];
  __shared__ __hip_bfloat16 vt[TTOK * 64];
  __shared__ float qt[32 * 64];
  int tid = threadIdx.x;
  int lane = tid & 63, wid = tid >> 6;
  int blk = blockIdx.x;
  int nchunk = blk & 127;
  int bh = blk >> 7;
  int h = bh & 7, b = bh >> 3;

  for (int idx = tid; idx < TTOK * 64; idx += 256) {
    int t = idx >> 6, d = idx & 63;
    size_t src = ((size_t)(b * TTOK + t)) * CDIM + h * 64 + d;
    kt[t * 68 + d] = kn[src];
    vt[t * 64 + d] = __float2bfloat16(vf[src]);
  }
  for (int idx = tid; idx < 32 * 64; idx += 256) {
    int nl = idx >> 6, d = idx & 63;
    qt[idx] = qn[((size_t)(b * 4096 + nchunk * 32 + nl)) * CDIM + h * 64 + d];
  }
  __syncthreads();

  float ls = fminf(fmaxf(ls_p[0], -2.0f), 2.0f);
  float scale = __expf(ls) * 0.125f;
  const float NEGINF = -__builtin_inff();
  float pv0 = pad[b * TTOK + lane];
  int t1ok = (lane + 64 < TTOK);
  float pv1 = t1ok ? pad[b * TTOK + lane + 64] : 1.0f;
  int t1 = t1ok ? lane + 64 : 0;

  for (int i = 0; i < 8; ++i) {
    int nl = wid * 8 + i;
    int n = nchunk * 32 + nl;
    size_t qbase = ((size_t)(b * 4096 + n)) * CDIM + h * 64;
    float s0 = 0.0f, s1 = 0.0f;
    const float4* qv4 = (const float4*)&qt[nl * 64];
    const float4* k0p = (const float4*)&kt[lane * 68];
    const float4* k1p = (const float4*)&kt[t1 * 68];
#pragma unroll
    for (int dg = 0; dg < 16; ++dg) {
      float4 qq = qv4[dg];
      float4 ka = k0p[dg];
      float4 kb = k1p[dg];
      s0 += qq.x * ka.x + qq.y * ka.y + qq.z * ka.z + qq.w * ka.w;
      s1 += qq.x * kb.x + qq.y * kb.y + qq.z * kb.z + qq.w * kb.w;
    }
    float v0 = (pv0 > 0.0f) ? NEGINF : s0 * scale;
    float v1 = (!t1ok || pv1 > 0.0f) ? NEGINF : s1 * scale;

    // single-chain wave top-3 (r1>=r2>=r3, with multiplicity)
    float r1 = fmaxf(v0, v1), r2 = fminf(v0, v1), r3 = NEGINF;
#pragma unroll
    for (int off = 32; off > 0; off >>= 1) {
      float u1 = __shfl_xor(r1, off, 64);
      float u2 = __shfl_xor(r2, off, 64);
      float u3 = __shfl_xor(r3, off, 64);
      float x1 = fmaxf(r1, u1), y1 = fminf(r1, u1);
      float x2 = fmaxf(r2, u2), y2 = fminf(r2, u2);
      float x3 = fmaxf(r3, u3);
      r1 = x1;
      r2 = fmaxf(y1, x2);
      r3 = fmaxf(fmaxf(fminf(y1, x2), y2), x3);
    }
    float m1 = r1;

    float acc = 0.0f, conf_h = 0.0f;
    if (m1 != NEGINF) {
      float thr = r3;   // 3rd largest with multiplicity == reference topv[-1]
      bool kp0 = (v0 >= thr) && (v0 != NEGINF);
      bool kp1 = (v1 >= thr) && (v1 != NEGINF);
      unsigned long long km0 = __ballot(kp0);
      unsigned long long km1 = __ballot(kp1);
      int cnt = __popcll(km0) + __popcll(km1);

      // closed-form S1/S2 over kept set {r1, r2, (cnt-2) x r3}; d1 = 0
      float d2 = r2 - m1, d3 = r3 - m1;
      int v2ok = (r2 != NEGINF), v3ok = (r3 != NEGINF);
      float e2 = v2ok ? __expf(d2) : 0.0f;
      float e3 = v3ok ? __expf(d3) : 0.0f;
      float fc = (float)(cnt - 2);
      float S1 = 1.0f + e2 + fc * e3;
      float S2 = (v2ok ? d2 * e2 : 0.0f) + fc * (v3ok ? d3 * e3 : 0.0f);

      float invS = 1.0f / S1;
      float maxp = invS;                       // max prob = exp(0)/S1
      float es = (__logf(S1) - S2 * invS) + (float)(TTOK - cnt) * 1.8420680743952367e-7f;
      float teff = fmaxf((float)cnt, 2.0f);
      float ent = fmaxf(es / __logf(teff), 0.0f);
      conf_h = fminf(fmaxf(maxp * (1.0f - ent), 0.0f), 1.0f);

      float e0 = kp0 ? __expf(v0 - m1) : 0.0f;
      float e1 = kp1 ? __expf(v1 - m1) : 0.0f;
      float a0 = e0 * invS, a1 = e1 * invS;
      unsigned long long m = km0;
      while (m) {
        int t = __builtin_ctzll(m);
        acc += __shfl(a0, t, 64) * __bfloat162float(vt[t * 64 + lane]);
        m &= m - 1;
      }
      m = km1;
      while (m) {
        int t = __builtin_ctzll(m);
        acc += __shfl(a1, t, 64) * __bfloat162float(vt[(t + 64) * 64 + lane]);
        m &= m - 1;
      }
    }
    if (lane == 0) confh[(size_t)h * MROWS + b * 4096 + n] = conf_h;
    aligned[qbase + lane] = __float2bfloat16(acc);
  }
}

// ---------------- bf16 MFMA GEMM, m97-style global_load_lds staging ----------------
// C = A(MxK bf16) @ BT^T + bias; BT is NxK bf16. M%128==0, N%128==0, K%32==0.
// mode 0: out bf16; mode 1: out fp32; mode 2: out d_out (fp32 if *flag else bf16) at ooff.
__global__ __launch_bounds__(256) void mfma_gemm(const short* __restrict__ A,
                                                 const short* __restrict__ BT,
                                                 const float* __restrict__ bias,
                                                 void* __restrict__ outp,
                                                 int mode, size_t ooff,
                                                 const int* __restrict__ flag,
                                                 const float* __restrict__ resid,
                                                 int M, int N, int K, int act) {
  __shared__ short As[128 * 32];   // unpadded: required by global_load_lds lane mapping
  __shared__ short Bs[128 * 32];
  int tid = threadIdx.x;
  int lane = tid & 63, w = tid >> 6;
  int wr = w >> 1, wc = w & 1;
  int bm = blockIdx.y * 128, bn = blockIdx.x * 128;
  float4v acc[4][4];
#pragma unroll
  for (int i = 0; i < 4; ++i)
#pragma unroll
    for (int j = 0; j < 4; ++j) acc[i][j] = (float4v){0.f, 0.f, 0.f, 0.f};

  int srow = w * 32 + (lane >> 2);
  int scol = (lane & 3) * 8;
  const short* Ag0 = A + (size_t)(bm + srow) * K + scol;
  const short* Ag1 = A + (size_t)(bm + srow + 16) * K + scol;
  const short* Bg0 = BT + (size_t)(bn + srow) * K + scol;
  const short* Bg1 = BT + (size_t)(bn + srow + 16) * K + scol;
  short* Al0 = As + w * 1024;
  short* Al1 = As + w * 1024 + 512;
  short* Bl0 = Bs + w * 1024;
  short* Bl1 = Bs + w * 1024 + 512;

  int m0 = wr * 64 + (lane & 15);
  int n0 = wc * 64 + (lane & 15);
  int kg = (lane >> 4) * 8;

  for (int k0 = 0; k0 < K; k0 += 32) {
    __syncthreads();
    gload16(Ag0 + k0, Al0);
    gload16(Ag1 + k0, Al1);
    gload16(Bg0 + k0, Bl0);
    gload16(Bg1 + k0, Bl1);
    __syncthreads();
    short8 af[4], bf[4];
#pragma unroll
    for (int mi = 0; mi < 4; ++mi) af[mi] = *(const short8*)&As[(m0 + mi * 16) * 32 + kg];
#pragma unroll
    for (int ni = 0; ni < 4; ++ni) bf[ni] = *(const short8*)&Bs[(n0 + ni * 16) * 32 + kg];
#pragma unroll
    for (int mi = 0; mi < 4; ++mi)
#pragma unroll
      for (int ni = 0; ni < 4; ++ni)
        acc[mi][ni] = __builtin_amdgcn_mfma_f32_16x16x32_bf16(af[mi], bf[ni], acc[mi][ni], 0, 0, 0);
  }

  int outf32 = (mode == 2) ? *flag : 0;
#pragma unroll
  for (int mi = 0; mi < 4; ++mi) {
#pragma unroll
    for (int ni = 0; ni < 4; ++ni) {
#pragma unroll
      for (int r = 0; r < 4; ++r) {
        int gr = bm + wr * 64 + mi * 16 + (lane >> 4) * 4 + r;
        int gc = bn + wc * 64 + ni * 16 + (lane & 15);
        float v = acc[mi][ni][r] + bias[gc];
        if (act == 1) v = 0.5f * v * (1.0f + erff(v * 0.70710678118654752f));
        if (resid) v += resid[(size_t)gr * N + gc];
        size_t oi = (size_t)gr * N + gc;
        if (mode == 0)      ((__hip_bfloat16*)outp)[oi] = __float2bfloat16(v);
        else if (mode == 1) ((float*)outp)[oi] = v;
        else {
          if (outf32) ((float*)outp)[ooff + oi] = v;
          else        ((__hip_bfloat16*)outp)[ooff + oi] = __float2bfloat16(v);
        }
      }
    }
  }
}

// ---------------- fused k & v fp32 GEMM (raw inputs), M=616 ----------------
__global__ __launch_bounds__(256) void kv_gemm(const void* __restrict__ text,
                                               const void* __restrict__ Wk,
                                               const void* __restrict__ Wv,
                                               const float* __restrict__ bk,
                                               const float* __restrict__ bv,
                                               float* __restrict__ kf,
                                               float* __restrict__ vf,
                                               const int* __restrict__ flag) {
  __shared__ float As[16][128];
  __shared__ float Bs[16][128];
  int f = *flag;
  int isv = blockIdx.x >> 2;
  int bn = (blockIdx.x & 3) * 128;
  int bm = blockIdx.y * 128;
  const void* B = isv ? Wv : Wk;
  const float* bias = isv ? bv : bk;
  float* C = isv ? vf : kf;
  int tid = threadIdx.x;
  int tx = tid & 15, ty = tid >> 4;
  float acc[8][8] = {};
  for (int k0 = 0; k0 < 512; k0 += 16) {
#pragma unroll
    for (int r = 0; r < 8; ++r) {
      int idx = tid + r * 256;
      int row = idx >> 4, kk = idx & 15;
      int gr = bm + row;
      As[kk][row] = (gr < BTOK) ? ldin(text, (size_t)gr * 512 + k0 + kk, f) : 0.0f;
    }
#pragma unroll
    for (int r = 0; r < 8; ++r) {
      int idx = tid + r * 256;
      int kk = idx >> 7, col = idx & 127;
      Bs[kk][col] = ldin(B, (size_t)(k0 + kk) * 512 + bn + col, f);
    }
    __syncthreads();
#pragma unroll
    for (int kk = 0; kk < 16; ++kk) {
      float ra[8], rb[8];
#pragma unroll
      for (int i = 0; i < 8; ++i) ra[i] = As[kk][ty * 8 + i];
#pragma unroll
      for (int j = 0; j < 8; ++j) rb[j] = Bs[kk][tx * 8 + j];
#pragma unroll
      for (int i = 0; i < 8; ++i)
#pragma unroll
        for (int j = 0; j < 8; ++j) acc[i][j] += ra[i] * rb[j];
    }
    __syncthreads();
  }
#pragma unroll
  for (int i = 0; i < 8; ++i) {
    int gr = bm + ty * 8 + i;
    if (gr >= BTOK) continue;
#pragma unroll
    for (int j = 0; j < 8; ++j) {
      int gc = bn + tx * 8 + j;
      C[(size_t)gr * 512 + gc] = acc[i][j] + bias[gc];
    }
  }
}

extern "C" void kernel_launch(void* const* d_in, const int* in_sizes, int n_in,
                              void* d_out, int out_size, void* d_ws, size_t ws_size,
                              hipStream_t stream) {
  const void* visual = d_in[0];
  const void* text   = d_in[1];

  char* wsb = (char*)d_ws;
  size_t off = 0;
  auto alloc = [&](size_t bytes) { char* p = wsb + off; off += (bytes + 63) & ~63ull; return p; };

  float* qpy  = (float*)alloc((size_t)NTOK * 4);                    // q -> proj -> y
  __hip_bfloat16* xb2 = (__hip_bfloat16*)alloc((size_t)NTOK * 2);   // x -> y2
  __hip_bfloat16* alb = (__hip_bfloat16*)alloc((size_t)NTOK * 2);   // aligned
  __hip_bfloat16* h1b = (__hip_bfloat16*)alloc((size_t)16384 * 2048 * 2); // MLP hidden (half-M chunk)
  float* kfb  = (float*)alloc((size_t)BTOK * CDIM * 4);
  float* vfb  = (float*)alloc((size_t)BTOK * CDIM * 4);
  float* padb = (float*)alloc(BTOK * 4);
  float* confh = (float*)alloc((size_t)8 * MROWS * 4);
  float* n1w = (float*)alloc(512 * 4);  float* n1b = (float*)alloc(512 * 4);
  float* n2w = (float*)alloc(512 * 4);  float* n2b = (float*)alloc(512 * 4);
  float* bq  = (float*)alloc(512 * 4);  float* bk = (float*)alloc(512 * 4);
  float* bv  = (float*)alloc(512 * 4);  float* bo = (float*)alloc(512 * 4);
  float* Wgf = (float*)alloc(512 * 4);  float* bg = (float*)alloc(16);
  float* lsb = (float*)alloc(16);
  float* b1  = (float*)alloc(2048 * 4); float* b2 = (float*)alloc(512 * 4);
  float* alp = (float*)alloc(16);
  __hip_bfloat16* WqT = (__hip_bfloat16*)alloc((size_t)262144 * 2);
  __hip_bfloat16* WoT = (__hip_bfloat16*)alloc((size_t)262144 * 2);
  __hip_bfloat16* W1T = (__hip_bfloat16*)alloc((size_t)1048576 * 2);
  __hip_bfloat16* W2T = (__hip_bfloat16*)alloc((size_t)1048576 * 2);
  int* flag = (int*)alloc(16);

  detect_kernel<<<1, 256, 0, stream>>>((const unsigned int*)text, flag);

  PCTab tab = {{
    {d_in[2], n1w, 512}, {d_in[3], n1b, 512}, {d_in[4], n2w, 512}, {d_in[5], n2b, 512},
    {d_in[7], bq, 512},  {d_in[9], bk, 512},  {d_in[11], bv, 512}, {d_in[13], bo, 512},
    {d_in[14], Wgf, 512}, {d_in[15], bg, 1},  {d_in[16], lsb, 1},
    {d_in[18], b1, 2048}, {d_in[20], b2, 512}, {d_in[21], alp, 1},
  }};
  cvt_params_kernel<<<14, 256, 0, stream>>>(tab, flag);

  tcvt_kernel<<<dim3(16, 16), 256, 0, stream>>>(d_in[6],  WqT, 512, 512, flag);
  tcvt_kernel<<<dim3(16, 16), 256, 0, stream>>>(d_in[12], WoT, 512, 512, flag);
  tcvt_kernel<<<dim3(64, 16), 256, 0, stream>>>(d_in[17], W1T, 512, 2048, flag);
  tcvt_kernel<<<dim3(16, 64), 256, 0, stream>>>(d_in[19], W2T, 2048, 512, flag);

  pad_kernel<<<BTOK, 256, 0, stream>>>(text, padb, flag);
  ln_kernel<<<MROWS, 256, 0, stream>>>(visual, n1w, n1b, xb2, flag);

  mfma_gemm<<<dim3(4, 256), 256, 0, stream>>>((const short*)xb2, (const short*)WqT, bq,
                                              qpy, 1, 0, flag, nullptr, MROWS, 512, 512, 0);
  kv_gemm<<<dim3(8, 5), 256, 0, stream>>>(text, d_in[8], d_in[10], bk, bv, kfb, vfb, flag);
  rownorm_kernel<<<MROWS, 256, 0, stream>>>(qpy);
  rownorm_kernel<<<BTOK, 256, 0, stream>>>(kfb);

  attn_kernel<<<8 * 8 * 128, 256, 0, stream>>>(qpy, kfb, vfb, padb, lsb, alb, confh);

  mfma_gemm<<<dim3(4, 256), 256, 0, stream>>>((const short*)alb, (const short*)WoT, bo,
                                              qpy, 1, 0, flag, nullptr, MROWS, 512, 512, 0);
  combine_ln_kernel<<<MROWS, 256, 0, stream>>>(xb2, qpy, confh, Wgf, bg, alp, n2w, n2b, xb2);

  // MLP in 2 chunks of 16384 rows
  for (int c = 0; c < 2; ++c) {
    const short* ychunk = (const short*)(xb2 + (size_t)c * 16384 * CDIM);
    const float* yres   = qpy + (size_t)c * 16384 * CDIM;
    mfma_gemm<<<dim3(16, 128), 256, 0, stream>>>(ychunk, (const short*)W1T, b1,
                                                 h1b, 0, 0, flag, nullptr, 16384, 2048, 512, 1);
    mfma_gemm<<<dim3(4, 128), 256, 0, stream>>>((const short*)h1b, (const short*)W2T, b2,
                                                d_out, 2, (size_t)c * 16384 * CDIM, flag, yres,
                                                16384, 512, 2048, 0);
  }
}

// Round 7
// 1056.020 us; speedup vs baseline: 1.1675x; 1.0465x over previous
//
#include <hip/hip_runtime.h>
#include <hip/hip_bf16.h>
#include <math.h>

// B=8, H=64, W=64, C=512 -> rows M = 32768; T=77, HH=8, DH=64, TOP_M=3
#define MROWS 32768
#define CDIM  512
#define TTOK  77
#define BTOK  616
#define NTOK  16777216

typedef __attribute__((ext_vector_type(8))) short short8;
typedef __attribute__((ext_vector_type(4))) float float4v;
typedef __attribute__((ext_vector_type(2))) float f2v;
typedef __attribute__((ext_vector_type(4))) unsigned short ushort4v;

__device__ __forceinline__ float ldin(const void* p, size_t i, int isf32) {
  return isf32 ? ((const float*)p)[i]
               : __bfloat162float(((const __hip_bfloat16*)p)[i]);
}

__device__ __forceinline__ unsigned short f2bf(float x) {
  __hip_bfloat16 h = __float2bfloat16(x);
  return *(unsigned short*)&h;
}

// async global->LDS, 16B per lane; LDS dest = uniform base + lane*16
__device__ __forceinline__ void gload16(const void* g, void* l) {
  __builtin_amdgcn_global_load_lds((const __attribute__((address_space(1))) unsigned int*)g,
                                   (__attribute__((address_space(3))) unsigned int*)l,
                                   16, 0, 0);
}

__device__ __forceinline__ float wave_sum(float v) {
#pragma unroll
  for (int off = 32; off > 0; off >>= 1) v += __shfl_xor(v, off, 64);
  return v;
}
__device__ __forceinline__ float wave_max(float v) {
#pragma unroll
  for (int off = 32; off > 0; off >>= 1) v = fmaxf(v, __shfl_xor(v, off, 64));
  return v;
}
__device__ __forceinline__ float block_sum256(float v) {
  __shared__ float red[4];
  int lane = threadIdx.x & 63, wid = threadIdx.x >> 6;
  float s = wave_sum(v);
  if (lane == 0) red[wid] = s;
  __syncthreads();
  s = red[0] + red[1] + red[2] + red[3];
  __syncthreads();
  return s;
}

// dtype detect (proven): 1 => fp32 inputs, 0 => bf16 inputs
__global__ __launch_bounds__(256) void detect_kernel(const unsigned int* __restrict__ t,
                                                     int* __restrict__ flag) {
  int insane = 0;
  for (int i = threadIdx.x; i < 4096; i += 256) {
    unsigned int lo = t[i] & 0xFFFFu;
    int e = (int)((lo >> 7) & 0xFFu);
    int sane = (lo == 0u) || (e >= 87 && e <= 147);
    insane += 1 - sane;
  }
  float tot = block_sum256((float)insane);
  if (threadIdx.x == 0) flag[0] = (tot > 1024.0f) ? 1 : 0;
}

// fused small-parameter convert: one block per segment
struct PC { const void* src; float* dst; int n; };
struct PCTab { PC e[14]; };
__global__ __launch_bounds__(256) void cvt_params_kernel(PCTab t, const int* __restrict__ flag) {
  int f = *flag;
  PC p = t.e[blockIdx.x];
  for (int i = threadIdx.x; i < p.n; i += 256) p.dst[i] = ldin(p.src, i, f);
}

// weight transpose+convert: in (KxN, raw dtype) -> out bf16 (NxK)
__global__ __launch_bounds__(256) void tcvt_kernel(const void* __restrict__ in,
                                                   __hip_bfloat16* __restrict__ out,
                                                   int K, int N, const int* __restrict__ flag) {
  __shared__ float tile[32][33];
  int tx = threadIdx.x & 31, ty = threadIdx.x >> 5;   // 32 x 8
  int k0 = blockIdx.y * 32, n0 = blockIdx.x * 32;
  int f = *flag;
#pragma unroll
  for (int r = 0; r < 4; ++r) {
    int k = k0 + ty + r * 8;
    tile[ty + r * 8][tx] = ldin(in, (size_t)k * N + n0 + tx, f);
  }
  __syncthreads();
#pragma unroll
  for (int r = 0; r < 4; ++r) {
    int n = n0 + ty + r * 8;
    out[(size_t)n * K + k0 + tx] = __float2bfloat16(tile[tx][ty + r * 8]);
  }
}

// pad mask straight from raw text
__global__ __launch_bounds__(256) void pad_kernel(const void* __restrict__ text,
                                                  float* __restrict__ pad,
                                                  const int* __restrict__ flag) {
  int row = blockIdx.x;
  size_t base = (size_t)row * CDIM;
  int tid = threadIdx.x;
  int f = *flag;
  float s = fabsf(ldin(text, base + tid, f)) + fabsf(ldin(text, base + 256 + tid, f));
  float tot = block_sum256(s);
  if (tid == 0) pad[row] = (tot <= 1e-6f) ? 1.0f : 0.0f;
}

// LayerNorm over C=512 (raw flag-dtype input) -> bf16 out
__global__ __launch_bounds__(256) void ln_kernel(const void* __restrict__ in,
                                                 const float* __restrict__ w,
                                                 const float* __restrict__ b,
                                                 __hip_bfloat16* __restrict__ out,
                                                 const int* __restrict__ flag) {
  int row = blockIdx.x;
  size_t base = (size_t)row * CDIM;
  int tid = threadIdx.x;
  int f = *flag;
  float v0 = ldin(in, base + tid, f);
  float v1 = ldin(in, base + 256 + tid, f);
  float tot = block_sum256(v0 + v1);
  float mu = tot * (1.0f / 512.0f);
  float d0 = v0 - mu, d1 = v1 - mu;
  float rs = rsqrtf(block_sum256(d0 * d0 + d1 * d1) * (1.0f / 512.0f) + 1e-5f);
  out[base + tid]       = __float2bfloat16(d0 * rs * w[tid]       + b[tid]);
  out[base + 256 + tid] = __float2bfloat16(d1 * rs * w[256 + tid] + b[256 + tid]);
}

__global__ __launch_bounds__(256) void rownorm_kernel(float* __restrict__ x) {
  int row = blockIdx.x;
  size_t base = (size_t)row * CDIM;
  int tid = threadIdx.x;
  float v0 = x[base + tid], v1 = x[base + 256 + tid];
  float sq = block_sum256(v0 * v0 + v1 * v1);
  float inv = 1.0f / fmaxf(sqrtf(sq), 1e-6f);
  x[base + tid] = v0 * inv;
  x[base + 256 + tid] = v1 * inv;
}

// fused gate + combine + LN2:
//   g   = alpha * sigmoid(x.Wg + bg) * (mean_h conf >= 0.35)
//   y   = x + g*proj   (fp32 back into proj, needed as MLP residual)
//   y2  = LN(y) -> bf16
__global__ __launch_bounds__(256) void combine_ln_kernel(const __hip_bfloat16* __restrict__ x,
                                                         float* __restrict__ proj,
                                                         const float* __restrict__ confh,
                                                         const float* __restrict__ Wg,
                                                         const float* __restrict__ bg,
                                                         const float* __restrict__ alpha_p,
                                                         const float* __restrict__ w,
                                                         const float* __restrict__ b,
                                                         __hip_bfloat16* __restrict__ y2) {
  int row = blockIdx.x;
  size_t base = (size_t)row * CDIM;
  int tid = threadIdx.x;
  float xv0 = __bfloat162float(x[base + tid]);
  float xv1 = __bfloat162float(x[base + 256 + tid]);
  float dot = block_sum256(xv0 * Wg[tid] + xv1 * Wg[256 + tid]);
  float csp = (tid < 8) ? confh[(size_t)tid * MROWS + row] : 0.0f;
  float cs = block_sum256(csp);
  float gate = 1.0f / (1.0f + __expf(-(dot + bg[0])));
  float byp = (cs * 0.125f >= 0.35f) ? 1.0f : 0.0f;
  float gv = alpha_p[0] * gate * byp;

  float v0 = xv0 + gv * proj[base + tid];
  float v1 = xv1 + gv * proj[base + 256 + tid];
  proj[base + tid] = v0;
  proj[base + 256 + tid] = v1;
  float tot = block_sum256(v0 + v1);
  float mu = tot * (1.0f / 512.0f);
  float d0 = v0 - mu, d1 = v1 - mu;
  float rs = rsqrtf(block_sum256(d0 * d0 + d1 * d1) * (1.0f / 512.0f) + 1e-5f);
  y2[base + tid]       = __float2bfloat16(d0 * rs * w[tid]       + b[tid]);
  y2[base + 256 + tid] = __float2bfloat16(d1 * rs * w[256 + tid] + b[256 + tid]);
}

// ---------------- attention (r6 structure + packed-fp32 QK + vec staging) --------
// Round-6 post-mortem: 221us @ VALUBusy 70% -> now VALU-ISSUE-bound (~155us issue
// time ~= instruction count). This round cuts VALU work, not stalls:
//  (a) QK dot via ext_vector float2 ops -> v_pk_fma_f32 (2 fp32/lane/clk; the
//      157.3TF fp32 peak path). 128 -> 64 FMA-class instrs/row. Association
//      changes by lane-pairing only (sub-ulp logit effect; selection robust).
//  (b) staging loops vectorized: float4 global loads + packed bf16 LDS writes
//      (d % 4 == 0 -> 16B/8B aligned).
// Selection logic (butterfly top-3, closed-form S1/S2) unchanged from r6.
// LDS 39424B, 4 blocks/CU. No forced waves-per-EU cap (round-1 spill lesson).
__global__ __launch_bounds__(256) void attn_kernel(const float* __restrict__ qn,
                                                   const float* __restrict__ kn,
                                                   const float* __restrict__ vf,
                                                   const float* __restrict__ pad,
                                                   const float* __restrict__ ls_p,
                                                   __hip_bfloat16* __restrict__ aligned,
                                                   float* __restrict__ confh) {
  __shared__ float kt[TTOK * 68];
  __shared__ __hip_bfloat16 vt[TTOK * 64];
  __shared__ float qt[32 * 64];
  int tid = threadIdx.x;
  int lane = tid & 63, wid = tid >> 6;
  int blk = blockIdx.x;
  int nchunk = blk & 127;
  int bh = blk >> 7;
  int h = bh & 7, b = bh >> 3;

  // K/V staging: 77 rows x 16 float4-chunks
  for (int idx4 = tid; idx4 < TTOK * 16; idx4 += 256) {
    int t = idx4 >> 4, d = (idx4 & 15) * 4;
    size_t src = ((size_t)(b * TTOK + t)) * CDIM + h * 64 + d;
    float4 kv = *(const float4*)&kn[src];
    float4 vv = *(const float4*)&vf[src];
    *(float4*)&kt[t * 68 + d] = kv;
    ushort4v pv;
    pv.x = f2bf(vv.x); pv.y = f2bf(vv.y); pv.z = f2bf(vv.z); pv.w = f2bf(vv.w);
    *(ushort4v*)&vt[t * 64 + d] = pv;
  }
  // Q staging: 32 rows x 16 float4-chunks
  for (int idx4 = tid; idx4 < 32 * 16; idx4 += 256) {
    int nl = idx4 >> 4, d = (idx4 & 15) * 4;
    float4 qv = *(const float4*)&qn[((size_t)(b * 4096 + nchunk * 32 + nl)) * CDIM + h * 64 + d];
    *(float4*)&qt[nl * 64 + d] = qv;
  }
  __syncthreads();

  float ls = fminf(fmaxf(ls_p[0], -2.0f), 2.0f);
  float scale = __expf(ls) * 0.125f;
  const float NEGINF = -__builtin_inff();
  float pv0 = pad[b * TTOK + lane];
  int t1ok = (lane + 64 < TTOK);
  float pv1 = t1ok ? pad[b * TTOK + lane + 64] : 1.0f;
  int t1 = t1ok ? lane + 64 : 0;

  for (int i = 0; i < 8; ++i) {
    int nl = wid * 8 + i;
    int n = nchunk * 32 + nl;
    size_t qbase = ((size_t)(b * 4096 + n)) * CDIM + h * 64;
    const float4* qv4 = (const float4*)&qt[nl * 64];
    const float4* k0p = (const float4*)&kt[lane * 68];
    const float4* k1p = (const float4*)&kt[t1 * 68];
    f2v s0p = {0.0f, 0.0f}, s1p = {0.0f, 0.0f};
#pragma unroll
    for (int dg = 0; dg < 16; ++dg) {
      float4 qq = qv4[dg];
      float4 ka = k0p[dg];
      float4 kb = k1p[dg];
      f2v qlo = {qq.x, qq.y}, qhi = {qq.z, qq.w};
      f2v kal = {ka.x, ka.y}, kah = {ka.z, ka.w};
      f2v kbl = {kb.x, kb.y}, kbh = {kb.z, kb.w};
      s0p += qlo * kal;
      s0p += qhi * kah;
      s1p += qlo * kbl;
      s1p += qhi * kbh;
    }
    float s0 = s0p.x + s0p.y, s1 = s1p.x + s1p.y;
    float v0 = (pv0 > 0.0f) ? NEGINF : s0 * scale;
    float v1 = (!t1ok || pv1 > 0.0f) ? NEGINF : s1 * scale;

    // single-chain wave top-3 (r1>=r2>=r3, with multiplicity)
    float r1 = fmaxf(v0, v1), r2 = fminf(v0, v1), r3 = NEGINF;
#pragma unroll
    for (int off = 32; off > 0; off >>= 1) {
      float u1 = __shfl_xor(r1, off, 64);
      float u2 = __shfl_xor(r2, off, 64);
      float u3 = __shfl_xor(r3, off, 64);
      float x1 = fmaxf(r1, u1), y1 = fminf(r1, u1);
      float x2 = fmaxf(r2, u2), y2 = fminf(r2, u2);
      float x3 = fmaxf(r3, u3);
      r1 = x1;
      r2 = fmaxf(y1, x2);
      r3 = fmaxf(fmaxf(fminf(y1, x2), y2), x3);
    }
    float m1 = r1;

    float acc = 0.0f, conf_h = 0.0f;
    if (m1 != NEGINF) {
      float thr = r3;   // 3rd largest with multiplicity == reference topv[-1]
      bool kp0 = (v0 >= thr) && (v0 != NEGINF);
      bool kp1 = (v1 >= thr) && (v1 != NEGINF);
      unsigned long long km0 = __ballot(kp0);
      unsigned long long km1 = __ballot(kp1);
      int cnt = __popcll(km0) + __popcll(km1);

      // closed-form S1/S2 over kept set {r1, r2, (cnt-2) x r3}; d1 = 0
      float d2 = r2 - m1, d3 = r3 - m1;
      int v2ok = (r2 != NEGINF), v3ok = (r3 != NEGINF);
      float e2 = v2ok ? __expf(d2) : 0.0f;
      float e3 = v3ok ? __expf(d3) : 0.0f;
      float fc = (float)(cnt - 2);
      float S1 = 1.0f + e2 + fc * e3;
      float S2 = (v2ok ? d2 * e2 : 0.0f) + fc * (v3ok ? d3 * e3 : 0.0f);

      float invS = 1.0f / S1;
      float maxp = invS;                       // max prob = exp(0)/S1
      float es = (__logf(S1) - S2 * invS) + (float)(TTOK - cnt) * 1.8420680743952367e-7f;
      float teff = fmaxf((float)cnt, 2.0f);
      float ent = fmaxf(es / __logf(teff), 0.0f);
      conf_h = fminf(fmaxf(maxp * (1.0f - ent), 0.0f), 1.0f);

      float e0 = kp0 ? __expf(v0 - m1) : 0.0f;
      float e1 = kp1 ? __expf(v1 - m1) : 0.0f;
      float a0 = e0 * invS, a1 = e1 * invS;
      unsigned long long m = km0;
      while (m) {
        int t = __builtin_ctzll(m);
        acc += __shfl(a0, t, 64) * __bfloat162float(vt[t * 64 + lane]);
        m &= m - 1;
      }
      m = km1;
      while (m) {
        int t = __builtin_ctzll(m);
        acc += __shfl(a1, t, 64) * __bfloat162float(vt[(t + 64) * 64 + lane]);
        m &= m - 1;
      }
    }
    if (lane == 0) confh[(size_t)h * MROWS + b * 4096 + n] = conf_h;
    aligned[qbase + lane] = __float2bfloat16(acc);
  }
}

// ---------------- bf16 MFMA GEMM, m97-style global_load_lds staging ----------------
// C = A(MxK bf16) @ BT^T + bias; BT is NxK bf16. M%128==0, N%128==0, K%32==0.
// mode 0: out bf16; mode 1: out fp32; mode 2: out d_out (fp32 if *flag else bf16) at ooff.
__global__ __launch_bounds__(256) void mfma_gemm(const short* __restrict__ A,
                                                 const short* __restrict__ BT,
                                                 const float* __restrict__ bias,
                                                 void* __restrict__ outp,
                                                 int mode, size_t ooff,
                                                 const int* __restrict__ flag,
                                                 const float* __restrict__ resid,
                                                 int M, int N, int K, int act) {
  __shared__ short As[128 * 32];   // unpadded: required by global_load_lds lane mapping
  __shared__ short Bs[128 * 32];
  int tid = threadIdx.x;
  int lane = tid & 63, w = tid >> 6;
  int wr = w >> 1, wc = w & 1;
  int bm = blockIdx.y * 128, bn = blockIdx.x * 128;
  float4v acc[4][4];
#pragma unroll
  for (int i = 0; i < 4; ++i)
#pragma unroll
    for (int j = 0; j < 4; ++j) acc[i][j] = (float4v){0.f, 0.f, 0.f, 0.f};

  int srow = w * 32 + (lane >> 2);
  int scol = (lane & 3) * 8;
  const short* Ag0 = A + (size_t)(bm + srow) * K + scol;
  const short* Ag1 = A + (size_t)(bm + srow + 16) * K + scol;
  const short* Bg0 = BT + (size_t)(bn + srow) * K + scol;
  const short* Bg1 = BT + (size_t)(bn + srow + 16) * K + scol;
  short* Al0 = As + w * 1024;
  short* Al1 = As + w * 1024 + 512;
  short* Bl0 = Bs + w * 1024;
  short* Bl1 = Bs + w * 1024 + 512;

  int m0 = wr * 64 + (lane & 15);
  int n0 = wc * 64 + (lane & 15);
  int kg = (lane >> 4) * 8;

  for (int k0 = 0; k0 < K; k0 += 32) {
    __syncthreads();
    gload16(Ag0 + k0, Al0);
    gload16(Ag1 + k0, Al1);
    gload16(Bg0 + k0, Bl0);
    gload16(Bg1 + k0, Bl1);
    __syncthreads();
    short8 af[4], bf[4];
#pragma unroll
    for (int mi = 0; mi < 4; ++mi) af[mi] = *(const short8*)&As[(m0 + mi * 16) * 32 + kg];
#pragma unroll
    for (int ni = 0; ni < 4; ++ni) bf[ni] = *(const short8*)&Bs[(n0 + ni * 16) * 32 + kg];
#pragma unroll
    for (int mi = 0; mi < 4; ++mi)
#pragma unroll
      for (int ni = 0; ni < 4; ++ni)
        acc[mi][ni] = __builtin_amdgcn_mfma_f32_16x16x32_bf16(af[mi], bf[ni], acc[mi][ni], 0, 0, 0);
  }

  int outf32 = (mode == 2) ? *flag : 0;
#pragma unroll
  for (int mi = 0; mi < 4; ++mi) {
#pragma unroll
    for (int ni = 0; ni < 4; ++ni) {
#pragma unroll
      for (int r = 0; r < 4; ++r) {
        int gr = bm + wr * 64 + mi * 16 + (lane >> 4) * 4 + r;
        int gc = bn + wc * 64 + ni * 16 + (lane & 15);
        float v = acc[mi][ni][r] + bias[gc];
        if (act == 1) v = 0.5f * v * (1.0f + erff(v * 0.70710678118654752f));
        if (resid) v += resid[(size_t)gr * N + gc];
        size_t oi = (size_t)gr * N + gc;
        if (mode == 0)      ((__hip_bfloat16*)outp)[oi] = __float2bfloat16(v);
        else if (mode == 1) ((float*)outp)[oi] = v;
        else {
          if (outf32) ((float*)outp)[ooff + oi] = v;
          else        ((__hip_bfloat16*)outp)[ooff + oi] = __float2bfloat16(v);
        }
      }
    }
  }
}

// ---------------- fused k & v fp32 GEMM (raw inputs), M=616 ----------------
__global__ __launch_bounds__(256) void kv_gemm(const void* __restrict__ text,
                                               const void* __restrict__ Wk,
                                               const void* __restrict__ Wv,
                                               const float* __restrict__ bk,
                                               const float* __restrict__ bv,
                                               float* __restrict__ kf,
                                               float* __restrict__ vf,
                                               const int* __restrict__ flag) {
  __shared__ float As[16][128];
  __shared__ float Bs[16][128];
  int f = *flag;
  int isv = blockIdx.x >> 2;
  int bn = (blockIdx.x & 3) * 128;
  int bm = blockIdx.y * 128;
  const void* B = isv ? Wv : Wk;
  const float* bias = isv ? bv : bk;
  float* C = isv ? vf : kf;
  int tid = threadIdx.x;
  int tx = tid & 15, ty = tid >> 4;
  float acc[8][8] = {};
  for (int k0 = 0; k0 < 512; k0 += 16) {
#pragma unroll
    for (int r = 0; r < 8; ++r) {
      int idx = tid + r * 256;
      int row = idx >> 4, kk = idx & 15;
      int gr = bm + row;
      As[kk][row] = (gr < BTOK) ? ldin(text, (size_t)gr * 512 + k0 + kk, f) : 0.0f;
    }
#pragma unroll
    for (int r = 0; r < 8; ++r) {
      int idx = tid + r * 256;
      int kk = idx >> 7, col = idx & 127;
      Bs[kk][col] = ldin(B, (size_t)(k0 + kk) * 512 + bn + col, f);
    }
    __syncthreads();
#pragma unroll
    for (int kk = 0; kk < 16; ++kk) {
      float ra[8], rb[8];
#pragma unroll
      for (int i = 0; i < 8; ++i) ra[i] = As[kk][ty * 8 + i];
#pragma unroll
      for (int j = 0; j < 8; ++j) rb[j] = Bs[kk][tx * 8 + j];
#pragma unroll
      for (int i = 0; i < 8; ++i)
#pragma unroll
        for (int j = 0; j < 8; ++j) acc[i][j] += ra[i] * rb[j];
    }
    __syncthreads();
  }
#pragma unroll
  for (int i = 0; i < 8; ++i) {
    int gr = bm + ty * 8 + i;
    if (gr >= BTOK) continue;
#pragma unroll
    for (int j = 0; j < 8; ++j) {
      int gc = bn + tx * 8 + j;
      C[(size_t)gr * 512 + gc] = acc[i][j] + bias[gc];
    }
  }
}

extern "C" void kernel_launch(void* const* d_in, const int* in_sizes, int n_in,
                              void* d_out, int out_size, void* d_ws, size_t ws_size,
                              hipStream_t stream) {
  const void* visual = d_in[0];
  const void* text   = d_in[1];

  char* wsb = (char*)d_ws;
  size_t off = 0;
  auto alloc = [&](size_t bytes) { char* p = wsb + off; off += (bytes + 63) & ~63ull; return p; };

  float* qpy  = (float*)alloc((size_t)NTOK * 4);                    // q -> proj -> y
  __hip_bfloat16* xb2 = (__hip_bfloat16*)alloc((size_t)NTOK * 2);   // x -> y2
  __hip_bfloat16* alb = (__hip_bfloat16*)alloc((size_t)NTOK * 2);   // aligned
  __hip_bfloat16* h1b = (__hip_bfloat16*)alloc((size_t)16384 * 2048 * 2); // MLP hidden (half-M chunk)
  float* kfb  = (float*)alloc((size_t)BTOK * CDIM * 4);
  float* vfb  = (float*)alloc((size_t)BTOK * CDIM * 4);
  float* padb = (float*)alloc(BTOK * 4);
  float* confh = (float*)alloc((size_t)8 * MROWS * 4);
  float* n1w = (float*)alloc(512 * 4);  float* n1b = (float*)alloc(512 * 4);
  float* n2w = (float*)alloc(512 * 4);  float* n2b = (float*)alloc(512 * 4);
  float* bq  = (float*)alloc(512 * 4);  float* bk = (float*)alloc(512 * 4);
  float* bv  = (float*)alloc(512 * 4);  float* bo = (float*)alloc(512 * 4);
  float* Wgf = (float*)alloc(512 * 4);  float* bg = (float*)alloc(16);
  float* lsb = (float*)alloc(16);
  float* b1  = (float*)alloc(2048 * 4); float* b2 = (float*)alloc(512 * 4);
  float* alp = (float*)alloc(16);
  __hip_bfloat16* WqT = (__hip_bfloat16*)alloc((size_t)262144 * 2);
  __hip_bfloat16* WoT = (__hip_bfloat16*)alloc((size_t)262144 * 2);
  __hip_bfloat16* W1T = (__hip_bfloat16*)alloc((size_t)1048576 * 2);
  __hip_bfloat16* W2T = (__hip_bfloat16*)alloc((size_t)1048576 * 2);
  int* flag = (int*)alloc(16);

  detect_kernel<<<1, 256, 0, stream>>>((const unsigned int*)text, flag);

  PCTab tab = {{
    {d_in[2], n1w, 512}, {d_in[3], n1b, 512}, {d_in[4], n2w, 512}, {d_in[5], n2b, 512},
    {d_in[7], bq, 512},  {d_in[9], bk, 512},  {d_in[11], bv, 512}, {d_in[13], bo, 512},
    {d_in[14], Wgf, 512}, {d_in[15], bg, 1},  {d_in[16], lsb, 1},
    {d_in[18], b1, 2048}, {d_in[20], b2, 512}, {d_in[21], alp, 1},
  }};
  cvt_params_kernel<<<14, 256, 0, stream>>>(tab, flag);

  tcvt_kernel<<<dim3(16, 16), 256, 0, stream>>>(d_in[6],  WqT, 512, 512, flag);
  tcvt_kernel<<<dim3(16, 16), 256, 0, stream>>>(d_in[12], WoT, 512, 512, flag);
  tcvt_kernel<<<dim3(64, 16), 256, 0, stream>>>(d_in[17], W1T, 512, 2048, flag);
  tcvt_kernel<<<dim3(16, 64), 256, 0, stream>>>(d_in[19], W2T, 2048, 512, flag);

  pad_kernel<<<BTOK, 256, 0, stream>>>(text, padb, flag);
  ln_kernel<<<MROWS, 256, 0, stream>>>(visual, n1w, n1b, xb2, flag);

  mfma_gemm<<<dim3(4, 256), 256, 0, stream>>>((const short*)xb2, (const short*)WqT, bq,
                                              qpy, 1, 0, flag, nullptr, MROWS, 512, 512, 0);
  kv_gemm<<<dim3(8, 5), 256, 0, stream>>>(text, d_in[8], d_in[10], bk, bv, kfb, vfb, flag);
  rownorm_kernel<<<MROWS, 256, 0, stream>>>(qpy);
  rownorm_kernel<<<BTOK, 256, 0, stream>>>(kfb);

  attn_kernel<<<8 * 8 * 128, 256, 0, stream>>>(qpy, kfb, vfb, padb, lsb, alb, confh);

  mfma_gemm<<<dim3(4, 256), 256, 0, stream>>>((const short*)alb, (const short*)WoT, bo,
                                              qpy, 1, 0, flag, nullptr, MROWS, 512, 512, 0);
  combine_ln_kernel<<<MROWS, 256, 0, stream>>>(xb2, qpy, confh, Wgf, bg, alp, n2w, n2b, xb2);

  // MLP in 2 chunks of 16384 rows
  for (int c = 0; c < 2; ++c) {
    const short* ychunk = (const short*)(xb2 + (size_t)c * 16384 * CDIM);
    const float* yres   = qpy + (size_t)c * 16384 * CDIM;
    mfma_gemm<<<dim3(16, 128), 256, 0, stream>>>(ychunk, (const short*)W1T, b1,
                                                 h1b, 0, 0, flag, nullptr, 16384, 2048, 512, 1);
    mfma_gemm<<<dim3(4, 128), 256, 0, stream>>>((const short*)h1b, (const short*)W2T, b2,
                                                d_out, 2, (size_t)c * 16384 * CDIM, flag, yres,
                                                16384, 512, 2048, 0);
  }
}

// Round 8
// 925.833 us; speedup vs baseline: 1.3317x; 1.1406x over previous
//
#include <hip/hip_runtime.h>
#include <hip/hip_bf16.h>
#include <math.h>

// B=8, H=64, W=64, C=512 -> rows M = 32768; T=77, HH=8, DH=64, TOP_M=3
#define MROWS 32768
#define CDIM  512
#define TTOK  77
#define BTOK  616
#define NTOK  16777216

typedef __attribute__((ext_vector_type(8))) short short8;
typedef __attribute__((ext_vector_type(4))) float float4v;
typedef __attribute__((ext_vector_type(2))) float f2v;
typedef __attribute__((ext_vector_type(4))) unsigned short ushort4v;

__device__ __forceinline__ float ldin(const void* p, size_t i, int isf32) {
  return isf32 ? ((const float*)p)[i]
               : __bfloat162float(((const __hip_bfloat16*)p)[i]);
}

__device__ __forceinline__ unsigned short f2bf(float x) {
  __hip_bfloat16 h = __float2bfloat16(x);
  return *(unsigned short*)&h;
}

// async global->LDS, 16B per lane; LDS dest = uniform base + lane*16
__device__ __forceinline__ void gload16(const void* g, void* l) {
  __builtin_amdgcn_global_load_lds((const __attribute__((address_space(1))) unsigned int*)g,
                                   (__attribute__((address_space(3))) unsigned int*)l,
                                   16, 0, 0);
}

__device__ __forceinline__ float wave_sum(float v) {
#pragma unroll
  for (int off = 32; off > 0; off >>= 1) v += __shfl_xor(v, off, 64);
  return v;
}
__device__ __forceinline__ float wave_max(float v) {
#pragma unroll
  for (int off = 32; off > 0; off >>= 1) v = fmaxf(v, __shfl_xor(v, off, 64));
  return v;
}
__device__ __forceinline__ float block_sum256(float v) {
  __shared__ float red[4];
  int lane = threadIdx.x & 63, wid = threadIdx.x >> 6;
  float s = wave_sum(v);
  if (lane == 0) red[wid] = s;
  __syncthreads();
  s = red[0] + red[1] + red[2] + red[3];
  __syncthreads();
  return s;
}

// dtype detect (proven): 1 => fp32 inputs, 0 => bf16 inputs
__global__ __launch_bounds__(256) void detect_kernel(const unsigned int* __restrict__ t,
                                                     int* __restrict__ flag) {
  int insane = 0;
  for (int i = threadIdx.x; i < 4096; i += 256) {
    unsigned int lo = t[i] & 0xFFFFu;
    int e = (int)((lo >> 7) & 0xFFu);
    int sane = (lo == 0u) || (e >= 87 && e <= 147);
    insane += 1 - sane;
  }
  float tot = block_sum256((float)insane);
  if (threadIdx.x == 0) flag[0] = (tot > 1024.0f) ? 1 : 0;
}

// fused small-parameter convert: one block per segment
struct PC { const void* src; float* dst; int n; };
struct PCTab { PC e[14]; };
__global__ __launch_bounds__(256) void cvt_params_kernel(PCTab t, const int* __restrict__ flag) {
  int f = *flag;
  PC p = t.e[blockIdx.x];
  for (int i = threadIdx.x; i < p.n; i += 256) p.dst[i] = ldin(p.src, i, f);
}

// weight transpose+convert: in (KxN, raw dtype) -> out bf16 (NxK)
__global__ __launch_bounds__(256) void tcvt_kernel(const void* __restrict__ in,
                                                   __hip_bfloat16* __restrict__ out,
                                                   int K, int N, const int* __restrict__ flag) {
  __shared__ float tile[32][33];
  int tx = threadIdx.x & 31, ty = threadIdx.x >> 5;   // 32 x 8
  int k0 = blockIdx.y * 32, n0 = blockIdx.x * 32;
  int f = *flag;
#pragma unroll
  for (int r = 0; r < 4; ++r) {
    int k = k0 + ty + r * 8;
    tile[ty + r * 8][tx] = ldin(in, (size_t)k * N + n0 + tx, f);
  }
  __syncthreads();
#pragma unroll
  for (int r = 0; r < 4; ++r) {
    int n = n0 + ty + r * 8;
    out[(size_t)n * K + k0 + tx] = __float2bfloat16(tile[tx][ty + r * 8]);
  }
}

// pad mask straight from raw text
__global__ __launch_bounds__(256) void pad_kernel(const void* __restrict__ text,
                                                  float* __restrict__ pad,
                                                  const int* __restrict__ flag) {
  int row = blockIdx.x;
  size_t base = (size_t)row * CDIM;
  int tid = threadIdx.x;
  int f = *flag;
  float s = fabsf(ldin(text, base + tid, f)) + fabsf(ldin(text, base + 256 + tid, f));
  float tot = block_sum256(s);
  if (tid == 0) pad[row] = (tot <= 1e-6f) ? 1.0f : 0.0f;
}

// LayerNorm over C=512 (raw flag-dtype input) -> bf16 out
__global__ __launch_bounds__(256) void ln_kernel(const void* __restrict__ in,
                                                 const float* __restrict__ w,
                                                 const float* __restrict__ b,
                                                 __hip_bfloat16* __restrict__ out,
                                                 const int* __restrict__ flag) {
  int row = blockIdx.x;
  size_t base = (size_t)row * CDIM;
  int tid = threadIdx.x;
  int f = *flag;
  float v0 = ldin(in, base + tid, f);
  float v1 = ldin(in, base + 256 + tid, f);
  float tot = block_sum256(v0 + v1);
  float mu = tot * (1.0f / 512.0f);
  float d0 = v0 - mu, d1 = v1 - mu;
  float rs = rsqrtf(block_sum256(d0 * d0 + d1 * d1) * (1.0f / 512.0f) + 1e-5f);
  out[base + tid]       = __float2bfloat16(d0 * rs * w[tid]       + b[tid]);
  out[base + 256 + tid] = __float2bfloat16(d1 * rs * w[256 + tid] + b[256 + tid]);
}

__global__ __launch_bounds__(256) void rownorm_kernel(float* __restrict__ x) {
  int row = blockIdx.x;
  size_t base = (size_t)row * CDIM;
  int tid = threadIdx.x;
  float v0 = x[base + tid], v1 = x[base + 256 + tid];
  float sq = block_sum256(v0 * v0 + v1 * v1);
  float inv = 1.0f / fmaxf(sqrtf(sq), 1e-6f);
  x[base + tid] = v0 * inv;
  x[base + 256 + tid] = v1 * inv;
}

// fused gate + combine + LN2:
//   g   = alpha * sigmoid(x.Wg + bg) * (mean_h conf >= 0.35)
//   y   = x + g*proj   (fp32 back into proj, needed as MLP residual)
//   y2  = LN(y) -> bf16
__global__ __launch_bounds__(256) void combine_ln_kernel(const __hip_bfloat16* __restrict__ x,
                                                         float* __restrict__ proj,
                                                         const float* __restrict__ confh,
                                                         const float* __restrict__ Wg,
                                                         const float* __restrict__ bg,
                                                         const float* __restrict__ alpha_p,
                                                         const float* __restrict__ w,
                                                         const float* __restrict__ b,
                                                         __hip_bfloat16* __restrict__ y2) {
  int row = blockIdx.x;
  size_t base = (size_t)row * CDIM;
  int tid = threadIdx.x;
  float xv0 = __bfloat162float(x[base + tid]);
  float xv1 = __bfloat162float(x[base + 256 + tid]);
  float dot = block_sum256(xv0 * Wg[tid] + xv1 * Wg[256 + tid]);
  float csp = (tid < 8) ? confh[(size_t)tid * MROWS + row] : 0.0f;
  float cs = block_sum256(csp);
  float gate = 1.0f / (1.0f + __expf(-(dot + bg[0])));
  float byp = (cs * 0.125f >= 0.35f) ? 1.0f : 0.0f;
  float gv = alpha_p[0] * gate * byp;

  float v0 = xv0 + gv * proj[base + tid];
  float v1 = xv1 + gv * proj[base + 256 + tid];
  proj[base + tid] = v0;
  proj[base + 256 + tid] = v1;
  float tot = block_sum256(v0 + v1);
  float mu = tot * (1.0f / 512.0f);
  float d0 = v0 - mu, d1 = v1 - mu;
  float rs = rsqrtf(block_sum256(d0 * d0 + d1 * d1) * (1.0f / 512.0f) + 1e-5f);
  y2[base + tid]       = __float2bfloat16(d0 * rs * w[tid]       + b[tid]);
  y2[base + 256 + tid] = __float2bfloat16(d1 * rs * w[256 + tid] + b[256 + tid]);
}

// ---------------- attention (r7, unchanged: packed-fp32 QK + vec staging) --------
__global__ __launch_bounds__(256) void attn_kernel(const float* __restrict__ qn,
                                                   const float* __restrict__ kn,
                                                   const float* __restrict__ vf,
                                                   const float* __restrict__ pad,
                                                   const float* __restrict__ ls_p,
                                                   __hip_bfloat16* __restrict__ aligned,
                                                   float* __restrict__ confh) {
  __shared__ float kt[TTOK * 68];
  __shared__ __hip_bfloat16 vt[TTOK * 64];
  __shared__ float qt[32 * 64];
  int tid = threadIdx.x;
  int lane = tid & 63, wid = tid >> 6;
  int blk = blockIdx.x;
  int nchunk = blk & 127;
  int bh = blk >> 7;
  int h = bh & 7, b = bh >> 3;

  // K/V staging: 77 rows x 16 float4-chunks
  for (int idx4 = tid; idx4 < TTOK * 16; idx4 += 256) {
    int t = idx4 >> 4, d = (idx4 & 15) * 4;
    size_t src = ((size_t)(b * TTOK + t)) * CDIM + h * 64 + d;
    float4 kv = *(const float4*)&kn[src];
    float4 vv = *(const float4*)&vf[src];
    *(float4*)&kt[t * 68 + d] = kv;
    ushort4v pv;
    pv.x = f2bf(vv.x); pv.y = f2bf(vv.y); pv.z = f2bf(vv.z); pv.w = f2bf(vv.w);
    *(ushort4v*)&vt[t * 64 + d] = pv;
  }
  // Q staging: 32 rows x 16 float4-chunks
  for (int idx4 = tid; idx4 < 32 * 16; idx4 += 256) {
    int nl = idx4 >> 4, d = (idx4 & 15) * 4;
    float4 qv = *(const float4*)&qn[((size_t)(b * 4096 + nchunk * 32 + nl)) * CDIM + h * 64 + d];
    *(float4*)&qt[nl * 64 + d] = qv;
  }
  __syncthreads();

  float ls = fminf(fmaxf(ls_p[0], -2.0f), 2.0f);
  float scale = __expf(ls) * 0.125f;
  const float NEGINF = -__builtin_inff();
  float pv0 = pad[b * TTOK + lane];
  int t1ok = (lane + 64 < TTOK);
  float pv1 = t1ok ? pad[b * TTOK + lane + 64] : 1.0f;
  int t1 = t1ok ? lane + 64 : 0;

  for (int i = 0; i < 8; ++i) {
    int nl = wid * 8 + i;
    int n = nchunk * 32 + nl;
    size_t qbase = ((size_t)(b * 4096 + n)) * CDIM + h * 64;
    const float4* qv4 = (const float4*)&qt[nl * 64];
    const float4* k0p = (const float4*)&kt[lane * 68];
    const float4* k1p = (const float4*)&kt[t1 * 68];
    f2v s0p = {0.0f, 0.0f}, s1p = {0.0f, 0.0f};
#pragma unroll
    for (int dg = 0; dg < 16; ++dg) {
      float4 qq = qv4[dg];
      float4 ka = k0p[dg];
      float4 kb = k1p[dg];
      f2v qlo = {qq.x, qq.y}, qhi = {qq.z, qq.w};
      f2v kal = {ka.x, ka.y}, kah = {ka.z, ka.w};
      f2v kbl = {kb.x, kb.y}, kbh = {kb.z, kb.w};
      s0p += qlo * kal;
      s0p += qhi * kah;
      s1p += qlo * kbl;
      s1p += qhi * kbh;
    }
    float s0 = s0p.x + s0p.y, s1 = s1p.x + s1p.y;
    float v0 = (pv0 > 0.0f) ? NEGINF : s0 * scale;
    float v1 = (!t1ok || pv1 > 0.0f) ? NEGINF : s1 * scale;

    // single-chain wave top-3 (r1>=r2>=r3, with multiplicity)
    float r1 = fmaxf(v0, v1), r2 = fminf(v0, v1), r3 = NEGINF;
#pragma unroll
    for (int off = 32; off > 0; off >>= 1) {
      float u1 = __shfl_xor(r1, off, 64);
      float u2 = __shfl_xor(r2, off, 64);
      float u3 = __shfl_xor(r3, off, 64);
      float x1 = fmaxf(r1, u1), y1 = fminf(r1, u1);
      float x2 = fmaxf(r2, u2), y2 = fminf(r2, u2);
      float x3 = fmaxf(r3, u3);
      r1 = x1;
      r2 = fmaxf(y1, x2);
      r3 = fmaxf(fmaxf(fminf(y1, x2), y2), x3);
    }
    float m1 = r1;

    float acc = 0.0f, conf_h = 0.0f;
    if (m1 != NEGINF) {
      float thr = r3;   // 3rd largest with multiplicity == reference topv[-1]
      bool kp0 = (v0 >= thr) && (v0 != NEGINF);
      bool kp1 = (v1 >= thr) && (v1 != NEGINF);
      unsigned long long km0 = __ballot(kp0);
      unsigned long long km1 = __ballot(kp1);
      int cnt = __popcll(km0) + __popcll(km1);

      // closed-form S1/S2 over kept set {r1, r2, (cnt-2) x r3}; d1 = 0
      float d2 = r2 - m1, d3 = r3 - m1;
      int v2ok = (r2 != NEGINF), v3ok = (r3 != NEGINF);
      float e2 = v2ok ? __expf(d2) : 0.0f;
      float e3 = v3ok ? __expf(d3) : 0.0f;
      float fc = (float)(cnt - 2);
      float S1 = 1.0f + e2 + fc * e3;
      float S2 = (v2ok ? d2 * e2 : 0.0f) + fc * (v3ok ? d3 * e3 : 0.0f);

      float invS = 1.0f / S1;
      float maxp = invS;                       // max prob = exp(0)/S1
      float es = (__logf(S1) - S2 * invS) + (float)(TTOK - cnt) * 1.8420680743952367e-7f;
      float teff = fmaxf((float)cnt, 2.0f);
      float ent = fmaxf(es / __logf(teff), 0.0f);
      conf_h = fminf(fmaxf(maxp * (1.0f - ent), 0.0f), 1.0f);

      float e0 = kp0 ? __expf(v0 - m1) : 0.0f;
      float e1 = kp1 ? __expf(v1 - m1) : 0.0f;
      float a0 = e0 * invS, a1 = e1 * invS;
      unsigned long long m = km0;
      while (m) {
        int t = __builtin_ctzll(m);
        acc += __shfl(a0, t, 64) * __bfloat162float(vt[t * 64 + lane]);
        m &= m - 1;
      }
      m = km1;
      while (m) {
        int t = __builtin_ctzll(m);
        acc += __shfl(a1, t, 64) * __bfloat162float(vt[(t + 64) * 64 + lane]);
        m &= m - 1;
      }
    }
    if (lane == 0) confh[(size_t)h * MROWS + b * 4096 + n] = conf_h;
    aligned[qbase + lane] = __float2bfloat16(acc);
  }
}

// ---------------- bf16 MFMA GEMM, m97-style global_load_lds staging ----------------
// C = A(MxK bf16) @ BT^T + bias; BT is NxK bf16. M%128==0, N%128==0, K%32==0.
// mode 0: out bf16; mode 1: out fp32; mode 2: out d_out (fp32 if *flag else bf16) at ooff.
__global__ __launch_bounds__(256) void mfma_gemm(const short* __restrict__ A,
                                                 const short* __restrict__ BT,
                                                 const float* __restrict__ bias,
                                                 void* __restrict__ outp,
                                                 int mode, size_t ooff,
                                                 const int* __restrict__ flag,
                                                 const float* __restrict__ resid,
                                                 int M, int N, int K, int act) {
  __shared__ short As[128 * 32];   // unpadded: required by global_load_lds lane mapping
  __shared__ short Bs[128 * 32];
  int tid = threadIdx.x;
  int lane = tid & 63, w = tid >> 6;
  int wr = w >> 1, wc = w & 1;
  int bm = blockIdx.y * 128, bn = blockIdx.x * 128;
  float4v acc[4][4];
#pragma unroll
  for (int i = 0; i < 4; ++i)
#pragma unroll
    for (int j = 0; j < 4; ++j) acc[i][j] = (float4v){0.f, 0.f, 0.f, 0.f};

  int srow = w * 32 + (lane >> 2);
  int scol = (lane & 3) * 8;
  const short* Ag0 = A + (size_t)(bm + srow) * K + scol;
  const short* Ag1 = A + (size_t)(bm + srow + 16) * K + scol;
  const short* Bg0 = BT + (size_t)(bn + srow) * K + scol;
  const short* Bg1 = BT + (size_t)(bn + srow + 16) * K + scol;
  short* Al0 = As + w * 1024;
  short* Al1 = As + w * 1024 + 512;
  short* Bl0 = Bs + w * 1024;
  short* Bl1 = Bs + w * 1024 + 512;

  int m0 = wr * 64 + (lane & 15);
  int n0 = wc * 64 + (lane & 15);
  int kg = (lane >> 4) * 8;

  for (int k0 = 0; k0 < K; k0 += 32) {
    __syncthreads();
    gload16(Ag0 + k0, Al0);
    gload16(Ag1 + k0, Al1);
    gload16(Bg0 + k0, Bl0);
    gload16(Bg1 + k0, Bl1);
    __syncthreads();
    short8 af[4], bf[4];
#pragma unroll
    for (int mi = 0; mi < 4; ++mi) af[mi] = *(const short8*)&As[(m0 + mi * 16) * 32 + kg];
#pragma unroll
    for (int ni = 0; ni < 4; ++ni) bf[ni] = *(const short8*)&Bs[(n0 + ni * 16) * 32 + kg];
#pragma unroll
    for (int mi = 0; mi < 4; ++mi)
#pragma unroll
      for (int ni = 0; ni < 4; ++ni)
        acc[mi][ni] = __builtin_amdgcn_mfma_f32_16x16x32_bf16(af[mi], bf[ni], acc[mi][ni], 0, 0, 0);
  }

  int outf32 = (mode == 2) ? *flag : 0;
#pragma unroll
  for (int mi = 0; mi < 4; ++mi) {
#pragma unroll
    for (int ni = 0; ni < 4; ++ni) {
#pragma unroll
      for (int r = 0; r < 4; ++r) {
        int gr = bm + wr * 64 + mi * 16 + (lane >> 4) * 4 + r;
        int gc = bn + wc * 64 + ni * 16 + (lane & 15);
        float v = acc[mi][ni][r] + bias[gc];
        if (act == 1) v = 0.5f * v * (1.0f + erff(v * 0.70710678118654752f));
        if (resid) v += resid[(size_t)gr * N + gc];
        size_t oi = (size_t)gr * N + gc;
        if (mode == 0)      ((__hip_bfloat16*)outp)[oi] = __float2bfloat16(v);
        else if (mode == 1) ((float*)outp)[oi] = v;
        else {
          if (outf32) ((float*)outp)[ooff + oi] = v;
          else        ((__hip_bfloat16*)outp)[ooff + oi] = __float2bfloat16(v);
        }
      }
    }
  }
}

// ---------------- fused k & v fp32 GEMM (raw inputs), M=616 ----------------
// Round-7 post-mortem: old 128x128 tiling = 40 blocks on 256 CUs (1.8% occupancy),
// 1.88M LDS bank conflicts (Bs stride-8 reads) -> 200us for 0.65 GFLOP (roofline
// ~5us). Fix: BM=32 x BN=64 tiles -> grid(16,20)=320 blocks; per-thread 2x4 acc;
// As padded [32][34] (2-way-free staging writes, aligned float2 reads); Bs [32][64]
// float4 reads (16 lanes x 4 banks = full coverage, 2-way free). Accumulation
// order over k is monotone 1-FMA-per-k == old kernel -> bit-identical results.
__global__ __launch_bounds__(256) void kv_gemm(const void* __restrict__ text,
                                               const void* __restrict__ Wk,
                                               const void* __restrict__ Wv,
                                               const float* __restrict__ bk,
                                               const float* __restrict__ bv,
                                               float* __restrict__ kf,
                                               float* __restrict__ vf,
                                               const int* __restrict__ flag) {
  __shared__ float As[32][34];
  __shared__ float Bs[32][64];
  int f = *flag;
  int isv = blockIdx.x >> 3;
  int bn = (blockIdx.x & 7) * 64;
  int bm = blockIdx.y * 32;
  const void* B = isv ? Wv : Wk;
  const float* bias = isv ? bv : bk;
  float* C = isv ? vf : kf;
  int tid = threadIdx.x;
  int tx = tid & 15, ty = tid >> 4;   // tx: 16 col-groups of 4; ty: 16 row-groups of 2
  float acc[2][4] = {};
  for (int k0 = 0; k0 < 512; k0 += 32) {
    // stage A: 32 rows x 32 kk (row-guarded), coalesced along kk
#pragma unroll
    for (int r = 0; r < 4; ++r) {
      int idx = tid + r * 256;
      int row = idx >> 5, kk = idx & 31;
      int gr = bm + row;
      As[kk][row] = (gr < BTOK) ? ldin(text, (size_t)gr * 512 + k0 + kk, f) : 0.0f;
    }
    // stage B: 32 kk x 64 cols, coalesced along col
#pragma unroll
    for (int r = 0; r < 8; ++r) {
      int idx = tid + r * 256;
      int kk = idx >> 6, col = idx & 63;
      Bs[kk][col] = ldin(B, (size_t)(k0 + kk) * 512 + bn + col, f);
    }
    __syncthreads();
#pragma unroll
    for (int kk = 0; kk < 32; ++kk) {
      f2v ra = *(const f2v*)&As[kk][ty * 2];
      float4 rb = *(const float4*)&Bs[kk][tx * 4];
      acc[0][0] += ra.x * rb.x; acc[0][1] += ra.x * rb.y;
      acc[0][2] += ra.x * rb.z; acc[0][3] += ra.x * rb.w;
      acc[1][0] += ra.y * rb.x; acc[1][1] += ra.y * rb.y;
      acc[1][2] += ra.y * rb.z; acc[1][3] += ra.y * rb.w;
    }
    __syncthreads();
  }
#pragma unroll
  for (int i = 0; i < 2; ++i) {
    int gr = bm + ty * 2 + i;
    if (gr >= BTOK) continue;
#pragma unroll
    for (int j = 0; j < 4; ++j) {
      int gc = bn + tx * 4 + j;
      C[(size_t)gr * 512 + gc] = acc[i][j] + bias[gc];
    }
  }
}

extern "C" void kernel_launch(void* const* d_in, const int* in_sizes, int n_in,
                              void* d_out, int out_size, void* d_ws, size_t ws_size,
                              hipStream_t stream) {
  const void* visual = d_in[0];
  const void* text   = d_in[1];

  char* wsb = (char*)d_ws;
  size_t off = 0;
  auto alloc = [&](size_t bytes) { char* p = wsb + off; off += (bytes + 63) & ~63ull; return p; };

  float* qpy  = (float*)alloc((size_t)NTOK * 4);                    // q -> proj -> y
  __hip_bfloat16* xb2 = (__hip_bfloat16*)alloc((size_t)NTOK * 2);   // x -> y2
  __hip_bfloat16* alb = (__hip_bfloat16*)alloc((size_t)NTOK * 2);   // aligned
  __hip_bfloat16* h1b = (__hip_bfloat16*)alloc((size_t)16384 * 2048 * 2); // MLP hidden (half-M chunk)
  float* kfb  = (float*)alloc((size_t)BTOK * CDIM * 4);
  float* vfb  = (float*)alloc((size_t)BTOK * CDIM * 4);
  float* padb = (float*)alloc(BTOK * 4);
  float* confh = (float*)alloc((size_t)8 * MROWS * 4);
  float* n1w = (float*)alloc(512 * 4);  float* n1b = (float*)alloc(512 * 4);
  float* n2w = (float*)alloc(512 * 4);  float* n2b = (float*)alloc(512 * 4);
  float* bq  = (float*)alloc(512 * 4);  float* bk = (float*)alloc(512 * 4);
  float* bv  = (float*)alloc(512 * 4);  float* bo = (float*)alloc(512 * 4);
  float* Wgf = (float*)alloc(512 * 4);  float* bg = (float*)alloc(16);
  float* lsb = (float*)alloc(16);
  float* b1  = (float*)alloc(2048 * 4); float* b2 = (float*)alloc(512 * 4);
  float* alp = (float*)alloc(16);
  __hip_bfloat16* WqT = (__hip_bfloat16*)alloc((size_t)262144 * 2);
  __hip_bfloat16* WoT = (__hip_bfloat16*)alloc((size_t)262144 * 2);
  __hip_bfloat16* W1T = (__hip_bfloat16*)alloc((size_t)1048576 * 2);
  __hip_bfloat16* W2T = (__hip_bfloat16*)alloc((size_t)1048576 * 2);
  int* flag = (int*)alloc(16);

  detect_kernel<<<1, 256, 0, stream>>>((const unsigned int*)text, flag);

  PCTab tab = {{
    {d_in[2], n1w, 512}, {d_in[3], n1b, 512}, {d_in[4], n2w, 512}, {d_in[5], n2b, 512},
    {d_in[7], bq, 512},  {d_in[9], bk, 512},  {d_in[11], bv, 512}, {d_in[13], bo, 512},
    {d_in[14], Wgf, 512}, {d_in[15], bg, 1},  {d_in[16], lsb, 1},
    {d_in[18], b1, 2048}, {d_in[20], b2, 512}, {d_in[21], alp, 1},
  }};
  cvt_params_kernel<<<14, 256, 0, stream>>>(tab, flag);

  tcvt_kernel<<<dim3(16, 16), 256, 0, stream>>>(d_in[6],  WqT, 512, 512, flag);
  tcvt_kernel<<<dim3(16, 16), 256, 0, stream>>>(d_in[12], WoT, 512, 512, flag);
  tcvt_kernel<<<dim3(64, 16), 256, 0, stream>>>(d_in[17], W1T, 512, 2048, flag);
  tcvt_kernel<<<dim3(16, 64), 256, 0, stream>>>(d_in[19], W2T, 2048, 512, flag);

  pad_kernel<<<BTOK, 256, 0, stream>>>(text, padb, flag);
  ln_kernel<<<MROWS, 256, 0, stream>>>(visual, n1w, n1b, xb2, flag);

  mfma_gemm<<<dim3(4, 256), 256, 0, stream>>>((const short*)xb2, (const short*)WqT, bq,
                                              qpy, 1, 0, flag, nullptr, MROWS, 512, 512, 0);
  kv_gemm<<<dim3(16, 20), 256, 0, stream>>>(text, d_in[8], d_in[10], bk, bv, kfb, vfb, flag);
  rownorm_kernel<<<MROWS, 256, 0, stream>>>(qpy);
  rownorm_kernel<<<BTOK, 256, 0, stream>>>(kfb);

  attn_kernel<<<8 * 8 * 128, 256, 0, stream>>>(qpy, kfb, vfb, padb, lsb, alb, confh);

  mfma_gemm<<<dim3(4, 256), 256, 0, stream>>>((const short*)alb, (const short*)WoT, bo,
                                              qpy, 1, 0, flag, nullptr, MROWS, 512, 512, 0);
  combine_ln_kernel<<<MROWS, 256, 0, stream>>>(xb2, qpy, confh, Wgf, bg, alp, n2w, n2b, xb2);

  // MLP in 2 chunks of 16384 rows
  for (int c = 0; c < 2; ++c) {
    const short* ychunk = (const short*)(xb2 + (size_t)c * 16384 * CDIM);
    const float* yres   = qpy + (size_t)c * 16384 * CDIM;
    mfma_gemm<<<dim3(16, 128), 256, 0, stream>>>(ychunk, (const short*)W1T, b1,
                                                 h1b, 0, 0, flag, nullptr, 16384, 2048, 512, 1);
    mfma_gemm<<<dim3(4, 128), 256, 0, stream>>>((const short*)h1b, (const short*)W2T, b2,
                                                d_out, 2, (size_t)c * 16384 * CDIM, flag, yres,
                                                16384, 512, 2048, 0);
  }
}

// Round 9
// 902.478 us; speedup vs baseline: 1.3662x; 1.0259x over previous
//
#include <hip/hip_runtime.h>
#include <hip/hip_bf16.h>
#include <math.h>

// B=8, H=64, W=64, C=512 -> rows M = 32768; T=77, HH=8, DH=64, TOP_M=3
#define MROWS 32768
#define CDIM  512
#define TTOK  77
#define BTOK  616
#define NTOK  16777216

typedef __attribute__((ext_vector_type(8))) short short8;
typedef __attribute__((ext_vector_type(4))) float float4v;
typedef __attribute__((ext_vector_type(2))) float f2v;
typedef __attribute__((ext_vector_type(4))) unsigned short ushort4v;

__device__ __forceinline__ float ldin(const void* p, size_t i, int isf32) {
  return isf32 ? ((const float*)p)[i]
               : __bfloat162float(((const __hip_bfloat16*)p)[i]);
}

__device__ __forceinline__ unsigned short f2bf(float x) {
  __hip_bfloat16 h = __float2bfloat16(x);
  return *(unsigned short*)&h;
}

// branchless GELU (exact-erf form) via Abramowitz-Stegun 7.1.26, |err|<=1.5e-7.
// Replaces libm erff (branchy, ~40 instrs, lane-divergent) in GEMM epilogues;
// output is stored as bf16 (ulp ~4e-3 at 1.0) so 1.5e-7 abs error is invisible.
__device__ __forceinline__ float gelu_erf(float v) {
  float x = fabsf(v) * 0.70710678118654752f;
  float t = __builtin_amdgcn_rcpf(1.0f + 0.3275911f * x);
  float p = t * (0.254829592f + t * (-0.284496736f +
            t * (1.421413741f + t * (-1.453152027f + t * 1.061405429f))));
  float erfp = 1.0f - p * __expf(-x * x);
  float er = copysignf(erfp, v);
  return 0.5f * v * (1.0f + er);
}

// async global->LDS, 16B per lane; LDS dest = uniform base + lane*16
__device__ __forceinline__ void gload16(const void* g, void* l) {
  __builtin_amdgcn_global_load_lds((const __attribute__((address_space(1))) unsigned int*)g,
                                   (__attribute__((address_space(3))) unsigned int*)l,
                                   16, 0, 0);
}

__device__ __forceinline__ float wave_sum(float v) {
#pragma unroll
  for (int off = 32; off > 0; off >>= 1) v += __shfl_xor(v, off, 64);
  return v;
}
__device__ __forceinline__ float wave_max(float v) {
#pragma unroll
  for (int off = 32; off > 0; off >>= 1) v = fmaxf(v, __shfl_xor(v, off, 64));
  return v;
}
__device__ __forceinline__ float block_sum256(float v) {
  __shared__ float red[4];
  int lane = threadIdx.x & 63, wid = threadIdx.x >> 6;
  float s = wave_sum(v);
  if (lane == 0) red[wid] = s;
  __syncthreads();
  s = red[0] + red[1] + red[2] + red[3];
  __syncthreads();
  return s;
}

// dtype detect (proven): 1 => fp32 inputs, 0 => bf16 inputs
__global__ __launch_bounds__(256) void detect_kernel(const unsigned int* __restrict__ t,
                                                     int* __restrict__ flag) {
  int insane = 0;
  for (int i = threadIdx.x; i < 4096; i += 256) {
    unsigned int lo = t[i] & 0xFFFFu;
    int e = (int)((lo >> 7) & 0xFFu);
    int sane = (lo == 0u) || (e >= 87 && e <= 147);
    insane += 1 - sane;
  }
  float tot = block_sum256((float)insane);
  if (threadIdx.x == 0) flag[0] = (tot > 1024.0f) ? 1 : 0;
}

// fused small-parameter convert: one block per segment
struct PC { const void* src; float* dst; int n; };
struct PCTab { PC e[14]; };
__global__ __launch_bounds__(256) void cvt_params_kernel(PCTab t, const int* __restrict__ flag) {
  int f = *flag;
  PC p = t.e[blockIdx.x];
  for (int i = threadIdx.x; i < p.n; i += 256) p.dst[i] = ldin(p.src, i, f);
}

// weight transpose+convert: in (KxN, raw dtype) -> out bf16 (NxK)
__global__ __launch_bounds__(256) void tcvt_kernel(const void* __restrict__ in,
                                                   __hip_bfloat16* __restrict__ out,
                                                   int K, int N, const int* __restrict__ flag) {
  __shared__ float tile[32][33];
  int tx = threadIdx.x & 31, ty = threadIdx.x >> 5;   // 32 x 8
  int k0 = blockIdx.y * 32, n0 = blockIdx.x * 32;
  int f = *flag;
#pragma unroll
  for (int r = 0; r < 4; ++r) {
    int k = k0 + ty + r * 8;
    tile[ty + r * 8][tx] = ldin(in, (size_t)k * N + n0 + tx, f);
  }
  __syncthreads();
#pragma unroll
  for (int r = 0; r < 4; ++r) {
    int n = n0 + ty + r * 8;
    out[(size_t)n * K + k0 + tx] = __float2bfloat16(tile[tx][ty + r * 8]);
  }
}

// pad mask straight from raw text
__global__ __launch_bounds__(256) void pad_kernel(const void* __restrict__ text,
                                                  float* __restrict__ pad,
                                                  const int* __restrict__ flag) {
  int row = blockIdx.x;
  size_t base = (size_t)row * CDIM;
  int tid = threadIdx.x;
  int f = *flag;
  float s = fabsf(ldin(text, base + tid, f)) + fabsf(ldin(text, base + 256 + tid, f));
  float tot = block_sum256(s);
  if (tid == 0) pad[row] = (tot <= 1e-6f) ? 1.0f : 0.0f;
}

// LayerNorm over C=512 (raw flag-dtype input) -> bf16 out
__global__ __launch_bounds__(256) void ln_kernel(const void* __restrict__ in,
                                                 const float* __restrict__ w,
                                                 const float* __restrict__ b,
                                                 __hip_bfloat16* __restrict__ out,
                                                 const int* __restrict__ flag) {
  int row = blockIdx.x;
  size_t base = (size_t)row * CDIM;
  int tid = threadIdx.x;
  int f = *flag;
  float v0 = ldin(in, base + tid, f);
  float v1 = ldin(in, base + 256 + tid, f);
  float tot = block_sum256(v0 + v1);
  float mu = tot * (1.0f / 512.0f);
  float d0 = v0 - mu, d1 = v1 - mu;
  float rs = rsqrtf(block_sum256(d0 * d0 + d1 * d1) * (1.0f / 512.0f) + 1e-5f);
  out[base + tid]       = __float2bfloat16(d0 * rs * w[tid]       + b[tid]);
  out[base + 256 + tid] = __float2bfloat16(d1 * rs * w[256 + tid] + b[256 + tid]);
}

__global__ __launch_bounds__(256) void rownorm_kernel(float* __restrict__ x) {
  int row = blockIdx.x;
  size_t base = (size_t)row * CDIM;
  int tid = threadIdx.x;
  float v0 = x[base + tid], v1 = x[base + 256 + tid];
  float sq = block_sum256(v0 * v0 + v1 * v1);
  float inv = 1.0f / fmaxf(sqrtf(sq), 1e-6f);
  x[base + tid] = v0 * inv;
  x[base + 256 + tid] = v1 * inv;
}

// fused gate + combine + LN2:
//   g   = alpha * sigmoid(x.Wg + bg) * (mean_h conf >= 0.35)
//   y   = x + g*proj   (fp32 back into proj, needed as MLP residual)
//   y2  = LN(y) -> bf16
__global__ __launch_bounds__(256) void combine_ln_kernel(const __hip_bfloat16* __restrict__ x,
                                                         float* __restrict__ proj,
                                                         const float* __restrict__ confh,
                                                         const float* __restrict__ Wg,
                                                         const float* __restrict__ bg,
                                                         const float* __restrict__ alpha_p,
                                                         const float* __restrict__ w,
                                                         const float* __restrict__ b,
                                                         __hip_bfloat16* __restrict__ y2) {
  int row = blockIdx.x;
  size_t base = (size_t)row * CDIM;
  int tid = threadIdx.x;
  float xv0 = __bfloat162float(x[base + tid]);
  float xv1 = __bfloat162float(x[base + 256 + tid]);
  float dot = block_sum256(xv0 * Wg[tid] + xv1 * Wg[256 + tid]);
  float csp = (tid < 8) ? confh[(size_t)tid * MROWS + row] : 0.0f;
  float cs = block_sum256(csp);
  float gate = 1.0f / (1.0f + __expf(-(dot + bg[0])));
  float byp = (cs * 0.125f >= 0.35f) ? 1.0f : 0.0f;
  float gv = alpha_p[0] * gate * byp;

  float v0 = xv0 + gv * proj[base + tid];
  float v1 = xv1 + gv * proj[base + 256 + tid];
  proj[base + tid] = v0;
  proj[base + 256 + tid] = v1;
  float tot = block_sum256(v0 + v1);
  float mu = tot * (1.0f / 512.0f);
  float d0 = v0 - mu, d1 = v1 - mu;
  float rs = rsqrtf(block_sum256(d0 * d0 + d1 * d1) * (1.0f / 512.0f) + 1e-5f);
  y2[base + tid]       = __float2bfloat16(d0 * rs * w[tid]       + b[tid]);
  y2[base + 256 + tid] = __float2bfloat16(d1 * rs * w[256 + tid] + b[256 + tid]);
}

// ---------------- attention (r7, unchanged: packed-fp32 QK + vec staging) --------
__global__ __launch_bounds__(256) void attn_kernel(const float* __restrict__ qn,
                                                   const float* __restrict__ kn,
                                                   const float* __restrict__ vf,
                                                   const float* __restrict__ pad,
                                                   const float* __restrict__ ls_p,
                                                   __hip_bfloat16* __restrict__ aligned,
                                                   float* __restrict__ confh) {
  __shared__ float kt[TTOK * 68];
  __shared__ __hip_bfloat16 vt[TTOK * 64];
  __shared__ float qt[32 * 64];
  int tid = threadIdx.x;
  int lane = tid & 63, wid = tid >> 6;
  int blk = blockIdx.x;
  int nchunk = blk & 127;
  int bh = blk >> 7;
  int h = bh & 7, b = bh >> 3;

  // K/V staging: 77 rows x 16 float4-chunks
  for (int idx4 = tid; idx4 < TTOK * 16; idx4 += 256) {
    int t = idx4 >> 4, d = (idx4 & 15) * 4;
    size_t src = ((size_t)(b * TTOK + t)) * CDIM + h * 64 + d;
    float4 kv = *(const float4*)&kn[src];
    float4 vv = *(const float4*)&vf[src];
    *(float4*)&kt[t * 68 + d] = kv;
    ushort4v pv;
    pv.x = f2bf(vv.x); pv.y = f2bf(vv.y); pv.z = f2bf(vv.z); pv.w = f2bf(vv.w);
    *(ushort4v*)&vt[t * 64 + d] = pv;
  }
  // Q staging: 32 rows x 16 float4-chunks
  for (int idx4 = tid; idx4 < 32 * 16; idx4 += 256) {
    int nl = idx4 >> 4, d = (idx4 & 15) * 4;
    float4 qv = *(const float4*)&qn[((size_t)(b * 4096 + nchunk * 32 + nl)) * CDIM + h * 64 + d];
    *(float4*)&qt[nl * 64 + d] = qv;
  }
  __syncthreads();

  float ls = fminf(fmaxf(ls_p[0], -2.0f), 2.0f);
  float scale = __expf(ls) * 0.125f;
  const float NEGINF = -__builtin_inff();
  float pv0 = pad[b * TTOK + lane];
  int t1ok = (lane + 64 < TTOK);
  float pv1 = t1ok ? pad[b * TTOK + lane + 64] : 1.0f;
  int t1 = t1ok ? lane + 64 : 0;

  for (int i = 0; i < 8; ++i) {
    int nl = wid * 8 + i;
    int n = nchunk * 32 + nl;
    size_t qbase = ((size_t)(b * 4096 + n)) * CDIM + h * 64;
    const float4* qv4 = (const float4*)&qt[nl * 64];
    const float4* k0p = (const float4*)&kt[lane * 68];
    const float4* k1p = (const float4*)&kt[t1 * 68];
    f2v s0p = {0.0f, 0.0f}, s1p = {0.0f, 0.0f};
#pragma unroll
    for (int dg = 0; dg < 16; ++dg) {
      float4 qq = qv4[dg];
      float4 ka = k0p[dg];
      float4 kb = k1p[dg];
      f2v qlo = {qq.x, qq.y}, qhi = {qq.z, qq.w};
      f2v kal = {ka.x, ka.y}, kah = {ka.z, ka.w};
      f2v kbl = {kb.x, kb.y}, kbh = {kb.z, kb.w};
      s0p += qlo * kal;
      s0p += qhi * kah;
      s1p += qlo * kbl;
      s1p += qhi * kbh;
    }
    float s0 = s0p.x + s0p.y, s1 = s1p.x + s1p.y;
    float v0 = (pv0 > 0.0f) ? NEGINF : s0 * scale;
    float v1 = (!t1ok || pv1 > 0.0f) ? NEGINF : s1 * scale;

    // single-chain wave top-3 (r1>=r2>=r3, with multiplicity)
    float r1 = fmaxf(v0, v1), r2 = fminf(v0, v1), r3 = NEGINF;
#pragma unroll
    for (int off = 32; off > 0; off >>= 1) {
      float u1 = __shfl_xor(r1, off, 64);
      float u2 = __shfl_xor(r2, off, 64);
      float u3 = __shfl_xor(r3, off, 64);
      float x1 = fmaxf(r1, u1), y1 = fminf(r1, u1);
      float x2 = fmaxf(r2, u2), y2 = fminf(r2, u2);
      float x3 = fmaxf(r3, u3);
      r1 = x1;
      r2 = fmaxf(y1, x2);
      r3 = fmaxf(fmaxf(fminf(y1, x2), y2), x3);
    }
    float m1 = r1;

    float acc = 0.0f, conf_h = 0.0f;
    if (m1 != NEGINF) {
      float thr = r3;   // 3rd largest with multiplicity == reference topv[-1]
      bool kp0 = (v0 >= thr) && (v0 != NEGINF);
      bool kp1 = (v1 >= thr) && (v1 != NEGINF);
      unsigned long long km0 = __ballot(kp0);
      unsigned long long km1 = __ballot(kp1);
      int cnt = __popcll(km0) + __popcll(km1);

      // closed-form S1/S2 over kept set {r1, r2, (cnt-2) x r3}; d1 = 0
      float d2 = r2 - m1, d3 = r3 - m1;
      int v2ok = (r2 != NEGINF), v3ok = (r3 != NEGINF);
      float e2 = v2ok ? __expf(d2) : 0.0f;
      float e3 = v3ok ? __expf(d3) : 0.0f;
      float fc = (float)(cnt - 2);
      float S1 = 1.0f + e2 + fc * e3;
      float S2 = (v2ok ? d2 * e2 : 0.0f) + fc * (v3ok ? d3 * e3 : 0.0f);

      float invS = 1.0f / S1;
      float maxp = invS;                       // max prob = exp(0)/S1
      float es = (__logf(S1) - S2 * invS) + (float)(TTOK - cnt) * 1.8420680743952367e-7f;
      float teff = fmaxf((float)cnt, 2.0f);
      float ent = fmaxf(es / __logf(teff), 0.0f);
      conf_h = fminf(fmaxf(maxp * (1.0f - ent), 0.0f), 1.0f);

      float e0 = kp0 ? __expf(v0 - m1) : 0.0f;
      float e1 = kp1 ? __expf(v1 - m1) : 0.0f;
      float a0 = e0 * invS, a1 = e1 * invS;
      unsigned long long m = km0;
      while (m) {
        int t = __builtin_ctzll(m);
        acc += __shfl(a0, t, 64) * __bfloat162float(vt[t * 64 + lane]);
        m &= m - 1;
      }
      m = km1;
      while (m) {
        int t = __builtin_ctzll(m);
        acc += __shfl(a1, t, 64) * __bfloat162float(vt[(t + 64) * 64 + lane]);
        m &= m - 1;
      }
    }
    if (lane == 0) confh[(size_t)h * MROWS + b * 4096 + n] = conf_h;
    aligned[qbase + lane] = __float2bfloat16(acc);
  }
}

// ---------------- bf16 MFMA GEMM, m97-style global_load_lds staging ----------------
// C = A(MxK bf16) @ BT^T + bias; BT is NxK bf16. M%128==0, N%128==0, K%32==0.
// mode 0: out bf16; mode 1: out fp32; mode 2: out d_out (fp32 if *flag else bf16) at ooff.
// Round-8 change: act==1 (GELU) uses branchless A-S erf approx (gelu_erf) instead
// of libm erff — 64 calls/thread made the W1 epilogue ~2x the MFMA main loop.
__global__ __launch_bounds__(256) void mfma_gemm(const short* __restrict__ A,
                                                 const short* __restrict__ BT,
                                                 const float* __restrict__ bias,
                                                 void* __restrict__ outp,
                                                 int mode, size_t ooff,
                                                 const int* __restrict__ flag,
                                                 const float* __restrict__ resid,
                                                 int M, int N, int K, int act) {
  __shared__ short As[128 * 32];   // unpadded: required by global_load_lds lane mapping
  __shared__ short Bs[128 * 32];
  int tid = threadIdx.x;
  int lane = tid & 63, w = tid >> 6;
  int wr = w >> 1, wc = w & 1;
  int bm = blockIdx.y * 128, bn = blockIdx.x * 128;
  float4v acc[4][4];
#pragma unroll
  for (int i = 0; i < 4; ++i)
#pragma unroll
    for (int j = 0; j < 4; ++j) acc[i][j] = (float4v){0.f, 0.f, 0.f, 0.f};

  int srow = w * 32 + (lane >> 2);
  int scol = (lane & 3) * 8;
  const short* Ag0 = A + (size_t)(bm + srow) * K + scol;
  const short* Ag1 = A + (size_t)(bm + srow + 16) * K + scol;
  const short* Bg0 = BT + (size_t)(bn + srow) * K + scol;
  const short* Bg1 = BT + (size_t)(bn + srow + 16) * K + scol;
  short* Al0 = As + w * 1024;
  short* Al1 = As + w * 1024 + 512;
  short* Bl0 = Bs + w * 1024;
  short* Bl1 = Bs + w * 1024 + 512;

  int m0 = wr * 64 + (lane & 15);
  int n0 = wc * 64 + (lane & 15);
  int kg = (lane >> 4) * 8;

  for (int k0 = 0; k0 < K; k0 += 32) {
    __syncthreads();
    gload16(Ag0 + k0, Al0);
    gload16(Ag1 + k0, Al1);
    gload16(Bg0 + k0, Bl0);
    gload16(Bg1 + k0, Bl1);
    __syncthreads();
    short8 af[4], bf[4];
#pragma unroll
    for (int mi = 0; mi < 4; ++mi) af[mi] = *(const short8*)&As[(m0 + mi * 16) * 32 + kg];
#pragma unroll
    for (int ni = 0; ni < 4; ++ni) bf[ni] = *(const short8*)&Bs[(n0 + ni * 16) * 32 + kg];
#pragma unroll
    for (int mi = 0; mi < 4; ++mi)
#pragma unroll
      for (int ni = 0; ni < 4; ++ni)
        acc[mi][ni] = __builtin_amdgcn_mfma_f32_16x16x32_bf16(af[mi], bf[ni], acc[mi][ni], 0, 0, 0);
  }

  int outf32 = (mode == 2) ? *flag : 0;
#pragma unroll
  for (int mi = 0; mi < 4; ++mi) {
#pragma unroll
    for (int ni = 0; ni < 4; ++ni) {
#pragma unroll
      for (int r = 0; r < 4; ++r) {
        int gr = bm + wr * 64 + mi * 16 + (lane >> 4) * 4 + r;
        int gc = bn + wc * 64 + ni * 16 + (lane & 15);
        float v = acc[mi][ni][r] + bias[gc];
        if (act == 1) v = gelu_erf(v);
        if (resid) v += resid[(size_t)gr * N + gc];
        size_t oi = (size_t)gr * N + gc;
        if (mode == 0)      ((__hip_bfloat16*)outp)[oi] = __float2bfloat16(v);
        else if (mode == 1) ((float*)outp)[oi] = v;
        else {
          if (outf32) ((float*)outp)[ooff + oi] = v;
          else        ((__hip_bfloat16*)outp)[ooff + oi] = __float2bfloat16(v);
        }
      }
    }
  }
}

// ---------------- fused k & v fp32 GEMM (raw inputs), M=616 ----------------
// r7 re-tile: BM=32 x BN=64, grid(16,20)=320 blocks, 2x4 acc/thread.
__global__ __launch_bounds__(256) void kv_gemm(const void* __restrict__ text,
                                               const void* __restrict__ Wk,
                                               const void* __restrict__ Wv,
                                               const float* __restrict__ bk,
                                               const float* __restrict__ bv,
                                               float* __restrict__ kf,
                                               float* __restrict__ vf,
                                               const int* __restrict__ flag) {
  __shared__ float As[32][34];
  __shared__ float Bs[32][64];
  int f = *flag;
  int isv = blockIdx.x >> 3;
  int bn = (blockIdx.x & 7) * 64;
  int bm = blockIdx.y * 32;
  const void* B = isv ? Wv : Wk;
  const float* bias = isv ? bv : bk;
  float* C = isv ? vf : kf;
  int tid = threadIdx.x;
  int tx = tid & 15, ty = tid >> 4;   // tx: 16 col-groups of 4; ty: 16 row-groups of 2
  float acc[2][4] = {};
  for (int k0 = 0; k0 < 512; k0 += 32) {
    // stage A: 32 rows x 32 kk (row-guarded), coalesced along kk
#pragma unroll
    for (int r = 0; r < 4; ++r) {
      int idx = tid + r * 256;
      int row = idx >> 5, kk = idx & 31;
      int gr = bm + row;
      As[kk][row] = (gr < BTOK) ? ldin(text, (size_t)gr * 512 + k0 + kk, f) : 0.0f;
    }
    // stage B: 32 kk x 64 cols, coalesced along col
#pragma unroll
    for (int r = 0; r < 8; ++r) {
      int idx = tid + r * 256;
      int kk = idx >> 6, col = idx & 63;
      Bs[kk][col] = ldin(B, (size_t)(k0 + kk) * 512 + bn + col, f);
    }
    __syncthreads();
#pragma unroll
    for (int kk = 0; kk < 32; ++kk) {
      f2v ra = *(const f2v*)&As[kk][ty * 2];
      float4 rb = *(const float4*)&Bs[kk][tx * 4];
      acc[0][0] += ra.x * rb.x; acc[0][1] += ra.x * rb.y;
      acc[0][2] += ra.x * rb.z; acc[0][3] += ra.x * rb.w;
      acc[1][0] += ra.y * rb.x; acc[1][1] += ra.y * rb.y;
      acc[1][2] += ra.y * rb.z; acc[1][3] += ra.y * rb.w;
    }
    __syncthreads();
  }
#pragma unroll
  for (int i = 0; i < 2; ++i) {
    int gr = bm + ty * 2 + i;
    if (gr >= BTOK) continue;
#pragma unroll
    for (int j = 0; j < 4; ++j) {
      int gc = bn + tx * 4 + j;
      C[(size_t)gr * 512 + gc] = acc[i][j] + bias[gc];
    }
  }
}

extern "C" void kernel_launch(void* const* d_in, const int* in_sizes, int n_in,
                              void* d_out, int out_size, void* d_ws, size_t ws_size,
                              hipStream_t stream) {
  const void* visual = d_in[0];
  const void* text   = d_in[1];

  char* wsb = (char*)d_ws;
  size_t off = 0;
  auto alloc = [&](size_t bytes) { char* p = wsb + off; off += (bytes + 63) & ~63ull; return p; };

  float* qpy  = (float*)alloc((size_t)NTOK * 4);                    // q -> proj -> y
  __hip_bfloat16* xb2 = (__hip_bfloat16*)alloc((size_t)NTOK * 2);   // x -> y2
  __hip_bfloat16* alb = (__hip_bfloat16*)alloc((size_t)NTOK * 2);   // aligned
  __hip_bfloat16* h1b = (__hip_bfloat16*)alloc((size_t)16384 * 2048 * 2); // MLP hidden (half-M chunk)
  float* kfb  = (float*)alloc((size_t)BTOK * CDIM * 4);
  float* vfb  = (float*)alloc((size_t)BTOK * CDIM * 4);
  float* padb = (float*)alloc(BTOK * 4);
  float* confh = (float*)alloc((size_t)8 * MROWS * 4);
  float* n1w = (float*)alloc(512 * 4);  float* n1b = (float*)alloc(512 * 4);
  float* n2w = (float*)alloc(512 * 4);  float* n2b = (float*)alloc(512 * 4);
  float* bq  = (float*)alloc(512 * 4);  float* bk = (float*)alloc(512 * 4);
  float* bv  = (float*)alloc(512 * 4);  float* bo = (float*)alloc(512 * 4);
  float* Wgf = (float*)alloc(512 * 4);  float* bg = (float*)alloc(16);
  float* lsb = (float*)alloc(16);
  float* b1  = (float*)alloc(2048 * 4); float* b2 = (float*)alloc(512 * 4);
  float* alp = (float*)alloc(16);
  __hip_bfloat16* WqT = (__hip_bfloat16*)alloc((size_t)262144 * 2);
  __hip_bfloat16* WoT = (__hip_bfloat16*)alloc((size_t)262144 * 2);
  __hip_bfloat16* W1T = (__hip_bfloat16*)alloc((size_t)1048576 * 2);
  __hip_bfloat16* W2T = (__hip_bfloat16*)alloc((size_t)1048576 * 2);
  int* flag = (int*)alloc(16);

  detect_kernel<<<1, 256, 0, stream>>>((const unsigned int*)text, flag);

  PCTab tab = {{
    {d_in[2], n1w, 512}, {d_in[3], n1b, 512}, {d_in[4], n2w, 512}, {d_in[5], n2b, 512},
    {d_in[7], bq, 512},  {d_in[9], bk, 512},  {d_in[11], bv, 512}, {d_in[13], bo, 512},
    {d_in[14], Wgf, 512}, {d_in[15], bg, 1},  {d_in[16], lsb, 1},
    {d_in[18], b1, 2048}, {d_in[20], b2, 512}, {d_in[21], alp, 1},
  }};
  cvt_params_kernel<<<14, 256, 0, stream>>>(tab, flag);

  tcvt_kernel<<<dim3(16, 16), 256, 0, stream>>>(d_in[6],  WqT, 512, 512, flag);
  tcvt_kernel<<<dim3(16, 16), 256, 0, stream>>>(d_in[12], WoT, 512, 512, flag);
  tcvt_kernel<<<dim3(64, 16), 256, 0, stream>>>(d_in[17], W1T, 512, 2048, flag);
  tcvt_kernel<<<dim3(16, 64), 256, 0, stream>>>(d_in[19], W2T, 2048, 512, flag);

  pad_kernel<<<BTOK, 256, 0, stream>>>(text, padb, flag);
  ln_kernel<<<MROWS, 256, 0, stream>>>(visual, n1w, n1b, xb2, flag);

  mfma_gemm<<<dim3(4, 256), 256, 0, stream>>>((const short*)xb2, (const short*)WqT, bq,
                                              qpy, 1, 0, flag, nullptr, MROWS, 512, 512, 0);
  kv_gemm<<<dim3(16, 20), 256, 0, stream>>>(text, d_in[8], d_in[10], bk, bv, kfb, vfb, flag);
  rownorm_kernel<<<MROWS, 256, 0, stream>>>(qpy);
  rownorm_kernel<<<BTOK, 256, 0, stream>>>(kfb);

  attn_kernel<<<8 * 8 * 128, 256, 0, stream>>>(qpy, kfb, vfb, padb, lsb, alb, confh);

  mfma_gemm<<<dim3(4, 256), 256, 0, stream>>>((const short*)alb, (const short*)WoT, bo,
                                              qpy, 1, 0, flag, nullptr, MROWS, 512, 512, 0);
  combine_ln_kernel<<<MROWS, 256, 0, stream>>>(xb2, qpy, confh, Wgf, bg, alp, n2w, n2b, xb2);

  // MLP in 2 chunks of 16384 rows
  for (int c = 0; c < 2; ++c) {
    const short* ychunk = (const short*)(xb2 + (size_t)c * 16384 * CDIM);
    const float* yres   = qpy + (size_t)c * 16384 * CDIM;
    mfma_gemm<<<dim3(16, 128), 256, 0, stream>>>(ychunk, (const short*)W1T, b1,
                                                 h1b, 0, 0, flag, nullptr, 16384, 2048, 512, 1);
    mfma_gemm<<<dim3(4, 128), 256, 0, stream>>>((const short*)h1b, (const short*)W2T, b2,
                                                d_out, 2, (size_t)c * 16384 * CDIM, flag, yres,
                                                16384, 512, 2048, 0);
  }
}